// Round 1
// baseline (647.002 us; speedup 1.0000x reference)
//
#include <hip/hip_runtime.h>

typedef unsigned short u16;
typedef unsigned int u32;
typedef short s16x8 __attribute__((ext_vector_type(8)));
typedef u16 u16x8 __attribute__((ext_vector_type(8)));
typedef float f32x4 __attribute__((ext_vector_type(4)));

#define TOK 8192
#define DM 1024
#define DI 2048
#define DS 16
#define DR 64
#define NCHUNK 16
#define CH 128

__device__ __forceinline__ u16 f2bf(float f) {
    u32 u = __float_as_uint(f);
    u32 r = (u + 0x7fffu + ((u >> 16) & 1u)) >> 16;
    return (u16)r;
}
__device__ __forceinline__ float bf2f(u16 h) {
    return __uint_as_float(((u32)h) << 16);
}
__device__ __forceinline__ float softplus_f(float x) {
    return (x > 15.f) ? x : log1pf(expf(x));
}
__device__ __forceinline__ void unpack8(const uint4 v, float* o) {
    o[0] = __uint_as_float(v.x << 16); o[1] = __uint_as_float(v.x & 0xffff0000u);
    o[2] = __uint_as_float(v.y << 16); o[3] = __uint_as_float(v.y & 0xffff0000u);
    o[4] = __uint_as_float(v.z << 16); o[5] = __uint_as_float(v.z & 0xffff0000u);
    o[6] = __uint_as_float(v.w << 16); o[7] = __uint_as_float(v.w & 0xffff0000u);
}
__device__ __forceinline__ void async16(u16* lds, const u16* g) {
    __builtin_amdgcn_global_load_lds(
        (const __attribute__((address_space(1))) void*)g,
        (__attribute__((address_space(3))) void*)lds, 16, 0, 0);
}

// ---------------- weight f32 -> bf16 ----------------
__global__ __launch_bounds__(256) void cvt_kernel(const float* __restrict__ src,
                                                  u16* __restrict__ dst, int n4) {
    int i = blockIdx.x * 256 + threadIdx.x;
    if (i >= n4) return;
    float4 v = ((const float4*)src)[i];
    ushort4 o;
    o.x = f2bf(v.x); o.y = f2bf(v.y); o.z = f2bf(v.z); o.w = f2bf(v.w);
    ((ushort4*)dst)[i] = o;
}

// ---------------- th[m], sd[n] ----------------
__global__ __launch_bounds__(256) void prep_kernel(const float* __restrict__ tau,
                                                   const float* __restrict__ log_decay,
                                                   float* __restrict__ th,
                                                   float* __restrict__ sd) {
    int i = blockIdx.x * 256 + threadIdx.x;
    if (i < TOK) th[i] = fmaxf(tau[i] * (1.f / 3600.f), 1e-4f);
    if (i < DM)  sd[i] = softplus_f(log_decay[i]);
}

// ---------------- LayerNorm -> bf16 ----------------
__global__ __launch_bounds__(256) void ln_kernel(const float* __restrict__ x,
                                                 const float* __restrict__ g,
                                                 const float* __restrict__ bb,
                                                 u16* __restrict__ xn) {
    const int tok = blockIdx.x;
    const float4 v = ((const float4*)(x + (size_t)tok * DM))[threadIdx.x];
    float s = v.x + v.y + v.z + v.w;
    float sq = v.x * v.x + v.y * v.y + v.z * v.z + v.w * v.w;
#pragma unroll
    for (int off = 32; off; off >>= 1) {
        s += __shfl_xor(s, off);
        sq += __shfl_xor(sq, off);
    }
    __shared__ float red[8];
    const int wv = threadIdx.x >> 6;
    if ((threadIdx.x & 63) == 0) { red[wv] = s; red[4 + wv] = sq; }
    __syncthreads();
    s = red[0] + red[1] + red[2] + red[3];
    sq = red[4] + red[5] + red[6] + red[7];
    const float mean = s * (1.f / DM);
    const float var = sq * (1.f / DM) - mean * mean;
    const float rstd = rsqrtf(var + 1e-5f);
    const float4 gv = ((const float4*)g)[threadIdx.x];
    const float4 bv = ((const float4*)bb)[threadIdx.x];
    ushort4 o;
    o.x = f2bf((v.x - mean) * rstd * gv.x + bv.x);
    o.y = f2bf((v.y - mean) * rstd * gv.y + bv.y);
    o.z = f2bf((v.z - mean) * rstd * gv.z + bv.z);
    o.w = f2bf((v.w - mean) * rstd * gv.w + bv.w);
    ((ushort4*)(xn + (size_t)tok * DM))[threadIdx.x] = o;
}

// ---------------- GEMM: C[M,N] = A[M,K] * W[N,K]^T (bf16 in, f32 acc) ----------------
// EPI 0: store bf16          EPI 1: softplus(acc+bias[col]) -> bf16
// EPI 2: f32 out = xres + acc * exp(-sd[col]*th[row])
template <int EPI>
__global__ __launch_bounds__(256) void gemm_bt(
    const u16* __restrict__ A, int lda,
    const u16* __restrict__ W,
    u16* __restrict__ Cb, float* __restrict__ Cf, int ldc,
    int M, int N, int K,
    const float* __restrict__ bias,
    const float* __restrict__ xres, const float* __restrict__ th,
    const float* __restrict__ sd) {
    __shared__ u16 As[128 * 32];
    __shared__ u16 Bs[128 * 32];
    const int tid = threadIdx.x;
    const int wave = tid >> 6, lane = tid & 63;
    const int bm = blockIdx.x, bn = blockIdx.y;
    const int srow = lane >> 2, scol = (lane & 3) * 8;
    const int wr = wave >> 1, wc = wave & 1;
    const int fl = lane & 15, fh = lane >> 4;

    f32x4 acc[4][4];
#pragma unroll
    for (int m = 0; m < 4; m++)
#pragma unroll
        for (int n = 0; n < 4; n++) acc[m][n] = f32x4{0.f, 0.f, 0.f, 0.f};

    int ra[2], rb[2];
    u16* ldsA[2]; u16* ldsB[2];
#pragma unroll
    for (int i = 0; i < 2; i++) {
        int r = (wave * 2 + i) * 16 + srow;
        ra[i] = min(bm * 128 + r, M - 1);
        rb[i] = min(bn * 128 + r, N - 1);
        ldsA[i] = As + (wave * 2 + i) * 512 + lane * 8;
        ldsB[i] = Bs + (wave * 2 + i) * 512 + lane * 8;
    }

    for (int k0 = 0; k0 < K; k0 += 32) {
        __syncthreads();
#pragma unroll
        for (int i = 0; i < 2; i++) {
            async16(ldsA[i], A + (size_t)ra[i] * lda + k0 + scol);
            async16(ldsB[i], W + (size_t)rb[i] * K + k0 + scol);
        }
        __syncthreads();
        s16x8 av[4], bv[4];
#pragma unroll
        for (int m = 0; m < 4; m++)
            av[m] = *(const s16x8*)(As + (wr * 64 + m * 16 + fl) * 32 + fh * 8);
#pragma unroll
        for (int n = 0; n < 4; n++)
            bv[n] = *(const s16x8*)(Bs + (wc * 64 + n * 16 + fl) * 32 + fh * 8);
#pragma unroll
        for (int m = 0; m < 4; m++)
#pragma unroll
            for (int n = 0; n < 4; n++)
                acc[m][n] = __builtin_amdgcn_mfma_f32_16x16x32_bf16(av[m], bv[n], acc[m][n], 0, 0, 0);
    }

#pragma unroll
    for (int m = 0; m < 4; m++) {
#pragma unroll
        for (int j = 0; j < 4; j++) {
            int row = bm * 128 + wr * 64 + m * 16 + fh * 4 + j;
            if (row >= M) continue;
#pragma unroll
            for (int n = 0; n < 4; n++) {
                int col = bn * 128 + wc * 64 + n * 16 + fl;
                if (col >= N) continue;
                float v = acc[m][n][j];
                size_t idx = (size_t)row * ldc + col;
                if (EPI == 0) {
                    Cb[idx] = f2bf(v);
                } else if (EPI == 1) {
                    Cb[idx] = f2bf(softplus_f(v + bias[col]));
                } else {
                    Cf[idx] = xres[idx] + v * expf(-sd[col] * th[row]);
                }
            }
        }
    }
}

// ---------------- causal depthwise conv + silu ----------------
__global__ __launch_bounds__(256) void conv_silu_kernel(const u16* __restrict__ xz,
                                                        const float* __restrict__ cw,
                                                        const float* __restrict__ cb,
                                                        u16* __restrict__ u) {
    const int tok = blockIdx.x;
    const int l = tok & 2047;
    const int d0 = threadIdx.x * 8;
    float acc[8];
#pragma unroll
    for (int e = 0; e < 8; e++) acc[e] = cb[d0 + e];
#pragma unroll
    for (int j = 0; j < 4; j++) {
        int ls = l + j - 3;
        if (ls < 0) continue;
        u16x8 v = *(const u16x8*)(xz + (size_t)(tok + j - 3) * (2 * DI) + d0);
#pragma unroll
        for (int e = 0; e < 8; e++) acc[e] += cw[(d0 + e) * 4 + j] * bf2f(v[e]);
    }
    u16x8 o;
#pragma unroll
    for (int e = 0; e < 8; e++) {
        float a = acc[e];
        o[e] = f2bf(a / (1.f + expf(-a)));
    }
    *(u16x8*)(u + (size_t)tok * DI + d0) = o;
}

// ---------------- selective scan, chunked ----------------
// pass A: per (chunk c, b, d): local scan from h=0 -> q[c][b][n][d], S[c][b][d]
__global__ __launch_bounds__(256) void scan_passA(const u16* __restrict__ delta,
                                                  const u16* __restrict__ u,
                                                  const u16* __restrict__ xdbl,
                                                  const float* __restrict__ A_log,
                                                  float* __restrict__ q,
                                                  float* __restrict__ Sarr) {
    const int d = blockIdx.x * 256 + threadIdx.x;
    const int b = blockIdx.y, c = blockIdx.z;
    float Av[16];
#pragma unroll
    for (int n = 0; n < 16; n++) Av[n] = -expf(A_log[d * 16 + n]);
    bool fast = true;
#pragma unroll
    for (int n = 0; n < 16; n++) fast = fast && (fabsf(Av[n] + (float)(n + 1)) < 1e-4f * (n + 1));
    const bool allfast = __all(fast);

    float h[16];
#pragma unroll
    for (int n = 0; n < 16; n++) h[n] = 0.f;
    float S = 0.f;
    const int l0 = c * CH;
    for (int l = l0; l < l0 + CH; ++l) {
        const size_t tok = (size_t)b * 2048 + l;
        float dt = bf2f(delta[tok * DI + d]);
        float uu = bf2f(u[tok * DI + d]);
        float du = dt * uu;
        const uint4* bp = (const uint4*)(xdbl + tok * 96 + 64);
        uint4 b0 = bp[0], b1 = bp[1];
        float Bv[16];
        unpack8(b0, Bv); unpack8(b1, Bv + 8);
        float e[16];
        if (allfast) {
            float r = expf(-dt);
            e[0] = r;
#pragma unroll
            for (int n = 1; n < 16; n++) e[n] = e[n - 1] * r;
        } else {
#pragma unroll
            for (int n = 0; n < 16; n++) e[n] = expf(dt * Av[n]);
        }
#pragma unroll
        for (int n = 0; n < 16; n++) h[n] = fmaf(e[n], h[n], du * Bv[n]);
        S += dt;
    }
    const size_t base = ((size_t)(c * 4 + b) * 16) * DI + d;
#pragma unroll
    for (int n = 0; n < 16; n++) q[base + (size_t)n * DI] = h[n];
    Sarr[(size_t)(c * 4 + b) * DI + d] = S;
}

// pass B: sequential combine over chunks -> hin[c][b][n][d]
__global__ __launch_bounds__(256) void scan_passB(const float* __restrict__ q,
                                                  const float* __restrict__ Sarr,
                                                  const float* __restrict__ A_log,
                                                  float* __restrict__ hin) {
    const int idx = blockIdx.x * 256 + threadIdx.x;  // 8192 chains
    const int d = idx & (DI - 1), b = idx >> 11;
    float Av[16];
#pragma unroll
    for (int n = 0; n < 16; n++) Av[n] = -expf(A_log[d * 16 + n]);
    float h[16];
#pragma unroll
    for (int n = 0; n < 16; n++) h[n] = 0.f;
    for (int c = 0; c < NCHUNK; c++) {
        const size_t base = ((size_t)(c * 4 + b) * 16) * DI + d;
#pragma unroll
        for (int n = 0; n < 16; n++) hin[base + (size_t)n * DI] = h[n];
        float S = Sarr[(size_t)(c * 4 + b) * DI + d];
#pragma unroll
        for (int n = 0; n < 16; n++) h[n] = fmaf(expf(Av[n] * S), h[n], q[base + (size_t)n * DI]);
    }
}

// pass C: replay with h0 = hin, emit yg = (y + u*D) * silu(z)  (bf16)
__global__ __launch_bounds__(256) void scan_passC(const u16* __restrict__ delta,
                                                  const u16* __restrict__ u,
                                                  const u16* __restrict__ xdbl,
                                                  const u16* __restrict__ xz,
                                                  const float* __restrict__ A_log,
                                                  const float* __restrict__ Dvec,
                                                  const float* __restrict__ hin,
                                                  u16* __restrict__ yg) {
    const int d = blockIdx.x * 256 + threadIdx.x;
    const int b = blockIdx.y, c = blockIdx.z;
    float Av[16];
#pragma unroll
    for (int n = 0; n < 16; n++) Av[n] = -expf(A_log[d * 16 + n]);
    bool fast = true;
#pragma unroll
    for (int n = 0; n < 16; n++) fast = fast && (fabsf(Av[n] + (float)(n + 1)) < 1e-4f * (n + 1));
    const bool allfast = __all(fast);
    const float Dd = Dvec[d];

    float h[16];
    const size_t hbase = ((size_t)(c * 4 + b) * 16) * DI + d;
#pragma unroll
    for (int n = 0; n < 16; n++) h[n] = hin[hbase + (size_t)n * DI];

    const int l0 = c * CH;
    for (int l = l0; l < l0 + CH; ++l) {
        const size_t tok = (size_t)b * 2048 + l;
        float dt = bf2f(delta[tok * DI + d]);
        float uu = bf2f(u[tok * DI + d]);
        float du = dt * uu;
        const uint4* bp = (const uint4*)(xdbl + tok * 96 + 64);
        uint4 b0 = bp[0], b1 = bp[1], c0 = bp[2], c1 = bp[3];
        float Bv[16], Cv[16];
        unpack8(b0, Bv); unpack8(b1, Bv + 8);
        unpack8(c0, Cv); unpack8(c1, Cv + 8);
        float e[16];
        if (allfast) {
            float r = expf(-dt);
            e[0] = r;
#pragma unroll
            for (int n = 1; n < 16; n++) e[n] = e[n - 1] * r;
        } else {
#pragma unroll
            for (int n = 0; n < 16; n++) e[n] = expf(dt * Av[n]);
        }
        float y = 0.f;
#pragma unroll
        for (int n = 0; n < 16; n++) {
            h[n] = fmaf(e[n], h[n], du * Bv[n]);
            y = fmaf(h[n], Cv[n], y);
        }
        float z = bf2f(xz[tok * (2 * DI) + DI + d]);
        float sz = z / (1.f + expf(-z));
        yg[tok * DI + d] = f2bf((y + uu * Dd) * sz);
    }
}

// ---------------- host ----------------
extern "C" void kernel_launch(void* const* d_in, const int* in_sizes, int n_in,
                              void* d_out, int out_size, void* d_ws, size_t ws_size,
                              hipStream_t stream) {
    const float* x = (const float*)d_in[0];
    const float* tau = (const float*)d_in[1];
    const float* ln_g = (const float*)d_in[2];
    const float* ln_b = (const float*)d_in[3];
    const float* in_proj_w = (const float*)d_in[4];
    const float* conv_w = (const float*)d_in[5];
    const float* conv_b = (const float*)d_in[6];
    const float* x_proj_w = (const float*)d_in[7];
    const float* dt_proj_w = (const float*)d_in[8];
    const float* dt_proj_b = (const float*)d_in[9];
    const float* A_log = (const float*)d_in[10];
    const float* Dvec = (const float*)d_in[11];
    const float* out_proj_w = (const float*)d_in[12];
    const float* log_decay = (const float*)d_in[13];
    float* out = (float*)d_out;

    char* ws = (char*)d_ws;
    size_t off = 0;
    auto alloc = [&](size_t bytes) -> void* {
        void* p = ws + off;
        off += (bytes + 255) & ~(size_t)255;
        return p;
    };
    u16* xn    = (u16*)alloc((size_t)TOK * DM * 2);        // 16 MB
    u16* w_in  = (u16*)alloc((size_t)2 * DI * DM * 2);     // 8 MB
    u16* w_xp  = (u16*)alloc((size_t)96 * DI * 2);
    u16* w_dt  = (u16*)alloc((size_t)DI * DR * 2);
    u16* w_out = (u16*)alloc((size_t)DM * DI * 2);         // 4 MB
    u16* xz    = (u16*)alloc((size_t)TOK * 2 * DI * 2);    // 64 MB
    u16* u     = (u16*)alloc((size_t)TOK * DI * 2);        // 32 MB
    u16* xdbl  = (u16*)alloc((size_t)TOK * 96 * 2);        // 1.5 MB
    u16* delta = (u16*)alloc((size_t)TOK * DI * 2);        // 32 MB
    float* q    = (float*)alloc((size_t)NCHUNK * 4 * 16 * DI * 4);  // 8 MB
    float* Sarr = (float*)alloc((size_t)NCHUNK * 4 * DI * 4);
    float* hin  = (float*)alloc((size_t)NCHUNK * 4 * 16 * DI * 4);  // 8 MB
    u16* yg    = (u16*)alloc((size_t)TOK * DI * 2);        // 32 MB
    float* th = (float*)alloc((size_t)TOK * 4);
    float* sd = (float*)alloc((size_t)DM * 4);

    // weights -> bf16
    cvt_kernel<<<4096, 256, 0, stream>>>(in_proj_w, w_in, (2 * DI * DM) / 4);
    cvt_kernel<<<192, 256, 0, stream>>>(x_proj_w, w_xp, (96 * DI) / 4);
    cvt_kernel<<<128, 256, 0, stream>>>(dt_proj_w, w_dt, (DI * DR) / 4);
    cvt_kernel<<<2048, 256, 0, stream>>>(out_proj_w, w_out, (DM * DI) / 4);
    prep_kernel<<<32, 256, 0, stream>>>(tau, log_decay, th, sd);

    // LN
    ln_kernel<<<TOK, 256, 0, stream>>>(x, ln_g, ln_b, xn);

    // in_proj: [8192,1024] x [4096,1024]^T -> xz bf16 [8192,4096]
    gemm_bt<0><<<dim3(64, 32), 256, 0, stream>>>(xn, DM, w_in, xz, nullptr, 2 * DI,
                                                 TOK, 2 * DI, DM, nullptr, nullptr, nullptr, nullptr);
    // conv + silu -> u bf16 [8192,2048]
    conv_silu_kernel<<<TOK, 256, 0, stream>>>(xz, conv_w, conv_b, u);

    // x_proj: [8192,2048] x [96,2048]^T -> xdbl bf16 [8192,96]
    gemm_bt<0><<<dim3(64, 1), 256, 0, stream>>>(u, DI, w_xp, xdbl, nullptr, 96,
                                                TOK, 96, DI, nullptr, nullptr, nullptr, nullptr);
    // dt_proj + softplus: [8192,64] x [2048,64]^T -> delta bf16 [8192,2048]
    gemm_bt<1><<<dim3(64, 16), 256, 0, stream>>>(xdbl, 96, w_dt, delta, nullptr, DI,
                                                 TOK, DI, DR, dt_proj_b, nullptr, nullptr, nullptr);

    // chunked selective scan
    scan_passA<<<dim3(8, 4, NCHUNK), 256, 0, stream>>>(delta, u, xdbl, A_log, q, Sarr);
    scan_passB<<<32, 256, 0, stream>>>(q, Sarr, A_log, hin);
    scan_passC<<<dim3(8, 4, NCHUNK), 256, 0, stream>>>(delta, u, xdbl, xz, A_log, Dvec, hin, yg);

    // out_proj + gate + residual: [8192,2048] x [1024,2048]^T -> out f32 [8192,1024]
    gemm_bt<2><<<dim3(64, 8), 256, 0, stream>>>(yg, DI, w_out, nullptr, out, DM,
                                                TOK, DM, DI, nullptr, x, th, sd);
}

// Round 2
// 526.565 us; speedup vs baseline: 1.2287x; 1.2287x over previous
//
#include <hip/hip_runtime.h>

typedef unsigned short u16;
typedef unsigned int u32;
typedef short s16x8 __attribute__((ext_vector_type(8)));
typedef u16 u16x8 __attribute__((ext_vector_type(8)));
typedef float f32x4 __attribute__((ext_vector_type(4)));

#define TOK 8192
#define DM 1024
#define DI 2048
#define DS 16
#define DR 64
#define NCHUNK 16
#define CH 128
#define XPN 96
#define XP_SPLIT 4
#define CONV_T 16

__device__ __forceinline__ u16 f2bf(float f) {
    u32 u = __float_as_uint(f);
    u32 r = (u + 0x7fffu + ((u >> 16) & 1u)) >> 16;
    return (u16)r;
}
__device__ __forceinline__ float bf2f(u16 h) {
    return __uint_as_float(((u32)h) << 16);
}
__device__ __forceinline__ float softplus_f(float x) {
    return (x > 15.f) ? x : log1pf(expf(x));
}
__device__ __forceinline__ void unpack8(const uint4 v, float* o) {
    o[0] = __uint_as_float(v.x << 16); o[1] = __uint_as_float(v.x & 0xffff0000u);
    o[2] = __uint_as_float(v.y << 16); o[3] = __uint_as_float(v.y & 0xffff0000u);
    o[4] = __uint_as_float(v.z << 16); o[5] = __uint_as_float(v.z & 0xffff0000u);
    o[6] = __uint_as_float(v.w << 16); o[7] = __uint_as_float(v.w & 0xffff0000u);
}
__device__ __forceinline__ void async16(u16* lds, const u16* g) {
    __builtin_amdgcn_global_load_lds(
        (const __attribute__((address_space(1))) void*)g,
        (__attribute__((address_space(3))) void*)lds, 16, 0, 0);
}

// ---------------- weight f32 -> bf16 ----------------
__global__ __launch_bounds__(256) void cvt_kernel(const float* __restrict__ src,
                                                  u16* __restrict__ dst, int n4) {
    int i = blockIdx.x * 256 + threadIdx.x;
    if (i >= n4) return;
    float4 v = ((const float4*)src)[i];
    ushort4 o;
    o.x = f2bf(v.x); o.y = f2bf(v.y); o.z = f2bf(v.z); o.w = f2bf(v.w);
    ((ushort4*)dst)[i] = o;
}

// ---------------- th[m], sd[n] ----------------
__global__ __launch_bounds__(256) void prep_kernel(const float* __restrict__ tau,
                                                   const float* __restrict__ log_decay,
                                                   float* __restrict__ th,
                                                   float* __restrict__ sd) {
    int i = blockIdx.x * 256 + threadIdx.x;
    if (i < TOK) th[i] = fmaxf(tau[i] * (1.f / 3600.f), 1e-4f);
    if (i < DM)  sd[i] = softplus_f(log_decay[i]);
}

// ---------------- LayerNorm -> bf16 ----------------
__global__ __launch_bounds__(256) void ln_kernel(const float* __restrict__ x,
                                                 const float* __restrict__ g,
                                                 const float* __restrict__ bb,
                                                 u16* __restrict__ xn) {
    const int tok = blockIdx.x;
    const float4 v = ((const float4*)(x + (size_t)tok * DM))[threadIdx.x];
    float s = v.x + v.y + v.z + v.w;
    float sq = v.x * v.x + v.y * v.y + v.z * v.z + v.w * v.w;
#pragma unroll
    for (int off = 32; off; off >>= 1) {
        s += __shfl_xor(s, off);
        sq += __shfl_xor(sq, off);
    }
    __shared__ float red[8];
    const int wv = threadIdx.x >> 6;
    if ((threadIdx.x & 63) == 0) { red[wv] = s; red[4 + wv] = sq; }
    __syncthreads();
    s = red[0] + red[1] + red[2] + red[3];
    sq = red[4] + red[5] + red[6] + red[7];
    const float mean = s * (1.f / DM);
    const float var = sq * (1.f / DM) - mean * mean;
    const float rstd = rsqrtf(var + 1e-5f);
    const float4 gv = ((const float4*)g)[threadIdx.x];
    const float4 bv = ((const float4*)bb)[threadIdx.x];
    ushort4 o;
    o.x = f2bf((v.x - mean) * rstd * gv.x + bv.x);
    o.y = f2bf((v.y - mean) * rstd * gv.y + bv.y);
    o.z = f2bf((v.z - mean) * rstd * gv.z + bv.z);
    o.w = f2bf((v.w - mean) * rstd * gv.w + bv.w);
    ((ushort4*)(xn + (size_t)tok * DM))[threadIdx.x] = o;
}

// ---------------- GEMM: C[M,N] = A[M,K] * W[N,K]^T (bf16 in, f32 acc) ----------------
template <int EPI>
__global__ __launch_bounds__(256) void gemm_bt(
    const u16* __restrict__ A, int lda,
    const u16* __restrict__ W,
    u16* __restrict__ Cb, float* __restrict__ Cf, int ldc,
    int M, int N, int K,
    const float* __restrict__ bias,
    const float* __restrict__ xres, const float* __restrict__ th,
    const float* __restrict__ sd) {
    __shared__ u16 As[128 * 32];
    __shared__ u16 Bs[128 * 32];
    const int tid = threadIdx.x;
    const int wave = tid >> 6, lane = tid & 63;
    const int bm = blockIdx.x, bn = blockIdx.y;
    const int srow = lane >> 2, scol = (lane & 3) * 8;
    const int wr = wave >> 1, wc = wave & 1;
    const int fl = lane & 15, fh = lane >> 4;

    f32x4 acc[4][4];
#pragma unroll
    for (int m = 0; m < 4; m++)
#pragma unroll
        for (int n = 0; n < 4; n++) acc[m][n] = f32x4{0.f, 0.f, 0.f, 0.f};

    int ra[2], rb[2];
    u16* ldsA[2]; u16* ldsB[2];
#pragma unroll
    for (int i = 0; i < 2; i++) {
        int r = (wave * 2 + i) * 16 + srow;
        ra[i] = min(bm * 128 + r, M - 1);
        rb[i] = min(bn * 128 + r, N - 1);
        ldsA[i] = As + (wave * 2 + i) * 512 + lane * 8;
        ldsB[i] = Bs + (wave * 2 + i) * 512 + lane * 8;
    }

    for (int k0 = 0; k0 < K; k0 += 32) {
        __syncthreads();
#pragma unroll
        for (int i = 0; i < 2; i++) {
            async16(ldsA[i], A + (size_t)ra[i] * lda + k0 + scol);
            async16(ldsB[i], W + (size_t)rb[i] * K + k0 + scol);
        }
        __syncthreads();
        s16x8 av[4], bv[4];
#pragma unroll
        for (int m = 0; m < 4; m++)
            av[m] = *(const s16x8*)(As + (wr * 64 + m * 16 + fl) * 32 + fh * 8);
#pragma unroll
        for (int n = 0; n < 4; n++)
            bv[n] = *(const s16x8*)(Bs + (wc * 64 + n * 16 + fl) * 32 + fh * 8);
#pragma unroll
        for (int m = 0; m < 4; m++)
#pragma unroll
            for (int n = 0; n < 4; n++)
                acc[m][n] = __builtin_amdgcn_mfma_f32_16x16x32_bf16(av[m], bv[n], acc[m][n], 0, 0, 0);
    }

#pragma unroll
    for (int m = 0; m < 4; m++) {
#pragma unroll
        for (int j = 0; j < 4; j++) {
            int row = bm * 128 + wr * 64 + m * 16 + fh * 4 + j;
            if (row >= M) continue;
#pragma unroll
            for (int n = 0; n < 4; n++) {
                int col = bn * 128 + wc * 64 + n * 16 + fl;
                if (col >= N) continue;
                float v = acc[m][n][j];
                size_t idx = (size_t)row * ldc + col;
                if (EPI == 0) {
                    Cb[idx] = f2bf(v);
                } else if (EPI == 1) {
                    Cb[idx] = f2bf(softplus_f(v + bias[col]));
                } else {
                    Cf[idx] = xres[idx] + v * expf(-sd[col] * th[row]);
                }
            }
        }
    }
}

// ---------------- x_proj split-K GEMM: part[sp] = u[.,Kc] * W[96,Kc]^T ----------------
__global__ __launch_bounds__(256) void xp_gemm(const u16* __restrict__ A,
                                               const u16* __restrict__ W,
                                               float* __restrict__ part) {
    __shared__ u16 As[128 * 64];  // 16 KB
    __shared__ u16 Bs[XPN * 64];  // 12 KB
    const int tid = threadIdx.x;
    const int wave = tid >> 6, lane = tid & 63;
    const int bm = blockIdx.x, sp = blockIdx.y;
    const int fl = lane & 15, fh = lane >> 4;
    const int trow = tid >> 3, tcol = (tid & 7) * 8;

    f32x4 acc[2][6];
#pragma unroll
    for (int m = 0; m < 2; m++)
#pragma unroll
        for (int n = 0; n < 6; n++) acc[m][n] = f32x4{0.f, 0.f, 0.f, 0.f};

    const int kbeg = sp * (DI / XP_SPLIT);
    for (int k0 = kbeg; k0 < kbeg + DI / XP_SPLIT; k0 += 64) {
        __syncthreads();
#pragma unroll
        for (int i = 0; i < 4; i++)
            async16(As + i * 2048 + tid * 8,
                    A + (size_t)(bm * 128 + i * 32 + trow) * DI + k0 + tcol);
#pragma unroll
        for (int i = 0; i < 3; i++)
            async16(Bs + i * 2048 + tid * 8,
                    W + (size_t)(i * 32 + trow) * DI + k0 + tcol);
        __syncthreads();
#pragma unroll
        for (int kk = 0; kk < 2; kk++) {
            s16x8 av[2], bv[6];
#pragma unroll
            for (int m = 0; m < 2; m++)
                av[m] = *(const s16x8*)(As + (wave * 32 + m * 16 + fl) * 64 + kk * 32 + fh * 8);
#pragma unroll
            for (int n = 0; n < 6; n++)
                bv[n] = *(const s16x8*)(Bs + (n * 16 + fl) * 64 + kk * 32 + fh * 8);
#pragma unroll
            for (int m = 0; m < 2; m++)
#pragma unroll
                for (int n = 0; n < 6; n++)
                    acc[m][n] = __builtin_amdgcn_mfma_f32_16x16x32_bf16(av[m], bv[n], acc[m][n], 0, 0, 0);
        }
    }
    float* dst = part + (size_t)sp * TOK * XPN;
#pragma unroll
    for (int m = 0; m < 2; m++)
#pragma unroll
        for (int j = 0; j < 4; j++) {
            int row = bm * 128 + wave * 32 + m * 16 + fh * 4 + j;
#pragma unroll
            for (int n = 0; n < 6; n++) {
                int col = n * 16 + fl;
                dst[(size_t)row * XPN + col] = acc[m][n][j];
            }
        }
}

__global__ __launch_bounds__(256) void xp_reduce(const float* __restrict__ part,
                                                 u16* __restrict__ out) {
    int i = blockIdx.x * 256 + threadIdx.x;
    if (i >= TOK * XPN) return;
    float s = 0.f;
#pragma unroll
    for (int sp = 0; sp < XP_SPLIT; sp++) s += part[(size_t)sp * TOK * XPN + i];
    out[i] = f2bf(s);
}

// ---------------- causal depthwise conv + silu (rolling window) ----------------
__global__ __launch_bounds__(256) void conv_silu_kernel(const u16* __restrict__ xz,
                                                        const float* __restrict__ cw,
                                                        const float* __restrict__ cb,
                                                        u16* __restrict__ u) {
    const int b = blockIdx.y;
    const int l0 = blockIdx.x * CONV_T;
    const int d0 = threadIdx.x * 8;
    float w0[8], w1[8], w2[8], w3[8], bias[8];
#pragma unroll
    for (int e = 0; e < 8; e++) {
        float4 wv = ((const float4*)cw)[d0 + e];
        w0[e] = wv.x; w1[e] = wv.y; w2[e] = wv.z; w3[e] = wv.w;
        bias[e] = cb[d0 + e];
    }
    float win[4][8];
    // preload rows l0-3 .. l0-1 into slots 1,2,3  (l0 % 4 == 0)
#pragma unroll
    for (int i = 0; i < 3; i++) {
        int l = l0 - 3 + i;
        int slot = (l0 + 1 + i) & 3;
        if (l < 0) {
#pragma unroll
            for (int e = 0; e < 8; e++) win[slot][e] = 0.f;
        } else {
            u16x8 v = *(const u16x8*)(xz + ((size_t)(b * 2048 + l)) * (2 * DI) + d0);
#pragma unroll
            for (int e = 0; e < 8; e++) win[slot][e] = bf2f(v[e]);
        }
    }
#pragma unroll
    for (int t = 0; t < CONV_T; t++) {
        const int l = l0 + t;
        const size_t tok = (size_t)b * 2048 + l;
        u16x8 v = *(const u16x8*)(xz + tok * (2 * DI) + d0);
        const int s3 = t & 3;  // row l
#pragma unroll
        for (int e = 0; e < 8; e++) win[s3][e] = bf2f(v[e]);
        const int s0 = (t + 1) & 3, s1 = (t + 2) & 3, s2 = (t + 3) & 3;
        u16x8 o;
#pragma unroll
        for (int e = 0; e < 8; e++) {
            float a = bias[e];
            a = fmaf(w0[e], win[s0][e], a);
            a = fmaf(w1[e], win[s1][e], a);
            a = fmaf(w2[e], win[s2][e], a);
            a = fmaf(w3[e], win[s3][e], a);
            o[e] = f2bf(a / (1.f + expf(-a)));
        }
        *(u16x8*)(u + tok * DI + d0) = o;
    }
}

// ---------------- selective scan, chunked ----------------
__global__ __launch_bounds__(256) void scan_passA(const u16* __restrict__ delta,
                                                  const u16* __restrict__ u,
                                                  const u16* __restrict__ xdbl,
                                                  const float* __restrict__ A_log,
                                                  float* __restrict__ q,
                                                  float* __restrict__ Sarr) {
    const int d = blockIdx.x * 256 + threadIdx.x;
    const int b = blockIdx.y, c = blockIdx.z;
    float Av[16];
#pragma unroll
    for (int n = 0; n < 16; n++) Av[n] = -expf(A_log[d * 16 + n]);
    bool fast = true;
#pragma unroll
    for (int n = 0; n < 16; n++) fast = fast && (fabsf(Av[n] + (float)(n + 1)) < 1e-4f * (n + 1));
    const bool allfast = __all(fast);

    float h[16];
#pragma unroll
    for (int n = 0; n < 16; n++) h[n] = 0.f;
    float S = 0.f;
    const int l0 = c * CH;
    for (int l = l0; l < l0 + CH; ++l) {
        const size_t tok = (size_t)b * 2048 + l;
        float dt = bf2f(delta[tok * DI + d]);
        float uu = bf2f(u[tok * DI + d]);
        float du = dt * uu;
        const uint4* bp = (const uint4*)(xdbl + tok * 96 + 64);
        uint4 b0 = bp[0], b1 = bp[1];
        float Bv[16];
        unpack8(b0, Bv); unpack8(b1, Bv + 8);
        float e[16];
        if (allfast) {
            float r = expf(-dt);
            e[0] = r;
#pragma unroll
            for (int n = 1; n < 16; n++) e[n] = e[n - 1] * r;
        } else {
#pragma unroll
            for (int n = 0; n < 16; n++) e[n] = expf(dt * Av[n]);
        }
#pragma unroll
        for (int n = 0; n < 16; n++) h[n] = fmaf(e[n], h[n], du * Bv[n]);
        S += dt;
    }
    const size_t base = ((size_t)(c * 4 + b) * 16) * DI + d;
#pragma unroll
    for (int n = 0; n < 16; n++) q[base + (size_t)n * DI] = h[n];
    Sarr[(size_t)(c * 4 + b) * DI + d] = S;
}

__global__ __launch_bounds__(256) void scan_passB(const float* __restrict__ q,
                                                  const float* __restrict__ Sarr,
                                                  const float* __restrict__ A_log,
                                                  float* __restrict__ hin) {
    const int idx = blockIdx.x * 256 + threadIdx.x;
    const int d = idx & (DI - 1), b = idx >> 11;
    float Av[16];
#pragma unroll
    for (int n = 0; n < 16; n++) Av[n] = -expf(A_log[d * 16 + n]);
    float h[16];
#pragma unroll
    for (int n = 0; n < 16; n++) h[n] = 0.f;
    for (int c = 0; c < NCHUNK; c++) {
        const size_t base = ((size_t)(c * 4 + b) * 16) * DI + d;
#pragma unroll
        for (int n = 0; n < 16; n++) hin[base + (size_t)n * DI] = h[n];
        float S = Sarr[(size_t)(c * 4 + b) * DI + d];
#pragma unroll
        for (int n = 0; n < 16; n++) h[n] = fmaf(expf(Av[n] * S), h[n], q[base + (size_t)n * DI]);
    }
}

__global__ __launch_bounds__(256) void scan_passC(const u16* __restrict__ delta,
                                                  const u16* __restrict__ u,
                                                  const u16* __restrict__ xdbl,
                                                  const u16* __restrict__ xz,
                                                  const float* __restrict__ A_log,
                                                  const float* __restrict__ Dvec,
                                                  const float* __restrict__ hin,
                                                  u16* __restrict__ yg) {
    const int d = blockIdx.x * 256 + threadIdx.x;
    const int b = blockIdx.y, c = blockIdx.z;
    float Av[16];
#pragma unroll
    for (int n = 0; n < 16; n++) Av[n] = -expf(A_log[d * 16 + n]);
    bool fast = true;
#pragma unroll
    for (int n = 0; n < 16; n++) fast = fast && (fabsf(Av[n] + (float)(n + 1)) < 1e-4f * (n + 1));
    const bool allfast = __all(fast);
    const float Dd = Dvec[d];

    float h[16];
    const size_t hbase = ((size_t)(c * 4 + b) * 16) * DI + d;
#pragma unroll
    for (int n = 0; n < 16; n++) h[n] = hin[hbase + (size_t)n * DI];

    const int l0 = c * CH;
    for (int l = l0; l < l0 + CH; ++l) {
        const size_t tok = (size_t)b * 2048 + l;
        float dt = bf2f(delta[tok * DI + d]);
        float uu = bf2f(u[tok * DI + d]);
        float du = dt * uu;
        const uint4* bp = (const uint4*)(xdbl + tok * 96 + 64);
        uint4 b0 = bp[0], b1 = bp[1], c0 = bp[2], c1 = bp[3];
        float Bv[16], Cv[16];
        unpack8(b0, Bv); unpack8(b1, Bv + 8);
        unpack8(c0, Cv); unpack8(c1, Cv + 8);
        float e[16];
        if (allfast) {
            float r = expf(-dt);
            e[0] = r;
#pragma unroll
            for (int n = 1; n < 16; n++) e[n] = e[n - 1] * r;
        } else {
#pragma unroll
            for (int n = 0; n < 16; n++) e[n] = expf(dt * Av[n]);
        }
        float y = 0.f;
#pragma unroll
        for (int n = 0; n < 16; n++) {
            h[n] = fmaf(e[n], h[n], du * Bv[n]);
            y = fmaf(h[n], Cv[n], y);
        }
        float z = bf2f(xz[tok * (2 * DI) + DI + d]);
        float sz = z / (1.f + expf(-z));
        yg[tok * DI + d] = f2bf((y + uu * Dd) * sz);
    }
}

// ---------------- host ----------------
extern "C" void kernel_launch(void* const* d_in, const int* in_sizes, int n_in,
                              void* d_out, int out_size, void* d_ws, size_t ws_size,
                              hipStream_t stream) {
    const float* x = (const float*)d_in[0];
    const float* tau = (const float*)d_in[1];
    const float* ln_g = (const float*)d_in[2];
    const float* ln_b = (const float*)d_in[3];
    const float* in_proj_w = (const float*)d_in[4];
    const float* conv_w = (const float*)d_in[5];
    const float* conv_b = (const float*)d_in[6];
    const float* x_proj_w = (const float*)d_in[7];
    const float* dt_proj_w = (const float*)d_in[8];
    const float* dt_proj_b = (const float*)d_in[9];
    const float* A_log = (const float*)d_in[10];
    const float* Dvec = (const float*)d_in[11];
    const float* out_proj_w = (const float*)d_in[12];
    const float* log_decay = (const float*)d_in[13];
    float* out = (float*)d_out;

    char* ws = (char*)d_ws;
    size_t off = 0;
    auto alloc = [&](size_t bytes) -> void* {
        void* p = ws + off;
        off += (bytes + 255) & ~(size_t)255;
        return p;
    };
    u16* xn    = (u16*)alloc((size_t)TOK * DM * 2);        // 16 MB (reused as xp_part)
    u16* w_in  = (u16*)alloc((size_t)2 * DI * DM * 2);     // 8 MB
    u16* w_xp  = (u16*)alloc((size_t)XPN * DI * 2);
    u16* w_dt  = (u16*)alloc((size_t)DI * DR * 2);
    u16* w_out = (u16*)alloc((size_t)DM * DI * 2);         // 4 MB
    u16* xz    = (u16*)alloc((size_t)TOK * 2 * DI * 2);    // 64 MB
    u16* u     = (u16*)alloc((size_t)TOK * DI * 2);        // 32 MB
    u16* xdbl  = (u16*)alloc((size_t)TOK * XPN * 2);       // 1.5 MB
    u16* delta = (u16*)alloc((size_t)TOK * DI * 2);        // 32 MB
    float* q    = (float*)alloc((size_t)NCHUNK * 4 * 16 * DI * 4);  // 8 MB
    float* Sarr = (float*)alloc((size_t)NCHUNK * 4 * DI * 4);
    float* hin  = (float*)alloc((size_t)NCHUNK * 4 * 16 * DI * 4);  // 8 MB
    u16* yg    = (u16*)alloc((size_t)TOK * DI * 2);        // 32 MB
    float* th = (float*)alloc((size_t)TOK * 4);
    float* sd = (float*)alloc((size_t)DM * 4);
    float* xp_part = (float*)xn;  // overlay: xn dead after in_proj; 12 MB <= 16 MB

    // weights -> bf16
    cvt_kernel<<<4096, 256, 0, stream>>>(in_proj_w, w_in, (2 * DI * DM) / 4);
    cvt_kernel<<<192, 256, 0, stream>>>(x_proj_w, w_xp, (XPN * DI) / 4);
    cvt_kernel<<<128, 256, 0, stream>>>(dt_proj_w, w_dt, (DI * DR) / 4);
    cvt_kernel<<<2048, 256, 0, stream>>>(out_proj_w, w_out, (DM * DI) / 4);
    prep_kernel<<<32, 256, 0, stream>>>(tau, log_decay, th, sd);

    // LN
    ln_kernel<<<TOK, 256, 0, stream>>>(x, ln_g, ln_b, xn);

    // in_proj: [8192,1024] x [4096,1024]^T -> xz bf16 [8192,4096]
    gemm_bt<0><<<dim3(64, 32), 256, 0, stream>>>(xn, DM, w_in, xz, nullptr, 2 * DI,
                                                 TOK, 2 * DI, DM, nullptr, nullptr, nullptr, nullptr);
    // conv + silu -> u bf16 [8192,2048]   (xn is dead from here; xp_part takes its space)
    conv_silu_kernel<<<dim3(2048 / CONV_T, 4), 256, 0, stream>>>(xz, conv_w, conv_b, u);

    // x_proj split-K: [8192,2048] x [96,2048]^T
    xp_gemm<<<dim3(64, XP_SPLIT), 256, 0, stream>>>(u, w_xp, xp_part);
    xp_reduce<<<(TOK * XPN + 255) / 256, 256, 0, stream>>>(xp_part, xdbl);

    // dt_proj + softplus: [8192,64] x [2048,64]^T -> delta bf16 [8192,2048]
    gemm_bt<1><<<dim3(64, 16), 256, 0, stream>>>(xdbl, XPN, w_dt, delta, nullptr, DI,
                                                 TOK, DI, DR, dt_proj_b, nullptr, nullptr, nullptr);

    // chunked selective scan
    scan_passA<<<dim3(8, 4, NCHUNK), 256, 0, stream>>>(delta, u, xdbl, A_log, q, Sarr);
    scan_passB<<<32, 256, 0, stream>>>(q, Sarr, A_log, hin);
    scan_passC<<<dim3(8, 4, NCHUNK), 256, 0, stream>>>(delta, u, xdbl, xz, A_log, Dvec, hin, yg);

    // out_proj + gate + residual: [8192,2048] x [1024,2048]^T -> out f32 [8192,1024]
    gemm_bt<2><<<dim3(64, 8), 256, 0, stream>>>(yg, DI, w_out, nullptr, out, DM,
                                                TOK, DM, DI, nullptr, x, th, sd);
}

// Round 3
// 418.550 us; speedup vs baseline: 1.5458x; 1.2581x over previous
//
#include <hip/hip_runtime.h>

typedef unsigned short u16;
typedef unsigned int u32;
typedef short s16x8 __attribute__((ext_vector_type(8)));
typedef u16 u16x8 __attribute__((ext_vector_type(8)));
typedef float f32x4 __attribute__((ext_vector_type(4)));

#define TOK 8192
#define DM 1024
#define DI 2048
#define DS 16
#define DR 64
#define NCHUNK 32
#define CH 64
#define XPN 96
#define XP_SPLIT 4
#define CONV_T 16

__device__ __forceinline__ u16 f2bf(float f) {
    u32 u = __float_as_uint(f);
    u32 r = (u + 0x7fffu + ((u >> 16) & 1u)) >> 16;
    return (u16)r;
}
__device__ __forceinline__ float bf2f(u16 h) {
    return __uint_as_float(((u32)h) << 16);
}
__device__ __forceinline__ float softplus_f(float x) {
    return (x > 15.f) ? x : log1pf(expf(x));
}
__device__ __forceinline__ void unpack8(const uint4 v, float* o) {
    o[0] = __uint_as_float(v.x << 16); o[1] = __uint_as_float(v.x & 0xffff0000u);
    o[2] = __uint_as_float(v.y << 16); o[3] = __uint_as_float(v.y & 0xffff0000u);
    o[4] = __uint_as_float(v.z << 16); o[5] = __uint_as_float(v.z & 0xffff0000u);
    o[6] = __uint_as_float(v.w << 16); o[7] = __uint_as_float(v.w & 0xffff0000u);
}
__device__ __forceinline__ void async16(u16* lds, const u16* g) {
    __builtin_amdgcn_global_load_lds(
        (const __attribute__((address_space(1))) void*)g,
        (__attribute__((address_space(3))) void*)lds, 16, 0, 0);
}

// ---------------- weight f32 -> bf16 ----------------
__global__ __launch_bounds__(256) void cvt_kernel(const float* __restrict__ src,
                                                  u16* __restrict__ dst, int n4) {
    int i = blockIdx.x * 256 + threadIdx.x;
    if (i >= n4) return;
    float4 v = ((const float4*)src)[i];
    ushort4 o;
    o.x = f2bf(v.x); o.y = f2bf(v.y); o.z = f2bf(v.z); o.w = f2bf(v.w);
    ((ushort4*)dst)[i] = o;
}

// ---------------- th[m], sd[n] ----------------
__global__ __launch_bounds__(256) void prep_kernel(const float* __restrict__ tau,
                                                   const float* __restrict__ log_decay,
                                                   float* __restrict__ th,
                                                   float* __restrict__ sd) {
    int i = blockIdx.x * 256 + threadIdx.x;
    if (i < TOK) th[i] = fmaxf(tau[i] * (1.f / 3600.f), 1e-4f);
    if (i < DM)  sd[i] = softplus_f(log_decay[i]);
}

// ---------------- LayerNorm -> bf16 ----------------
__global__ __launch_bounds__(256) void ln_kernel(const float* __restrict__ x,
                                                 const float* __restrict__ g,
                                                 const float* __restrict__ bb,
                                                 u16* __restrict__ xn) {
    const int tok = blockIdx.x;
    const float4 v = ((const float4*)(x + (size_t)tok * DM))[threadIdx.x];
    float s = v.x + v.y + v.z + v.w;
    float sq = v.x * v.x + v.y * v.y + v.z * v.z + v.w * v.w;
#pragma unroll
    for (int off = 32; off; off >>= 1) {
        s += __shfl_xor(s, off);
        sq += __shfl_xor(sq, off);
    }
    __shared__ float red[8];
    const int wv = threadIdx.x >> 6;
    if ((threadIdx.x & 63) == 0) { red[wv] = s; red[4 + wv] = sq; }
    __syncthreads();
    s = red[0] + red[1] + red[2] + red[3];
    sq = red[4] + red[5] + red[6] + red[7];
    const float mean = s * (1.f / DM);
    const float var = sq * (1.f / DM) - mean * mean;
    const float rstd = rsqrtf(var + 1e-5f);
    const float4 gv = ((const float4*)g)[threadIdx.x];
    const float4 bv = ((const float4*)bb)[threadIdx.x];
    ushort4 o;
    o.x = f2bf((v.x - mean) * rstd * gv.x + bv.x);
    o.y = f2bf((v.y - mean) * rstd * gv.y + bv.y);
    o.z = f2bf((v.z - mean) * rstd * gv.z + bv.z);
    o.w = f2bf((v.w - mean) * rstd * gv.w + bv.w);
    ((ushort4*)(xn + (size_t)tok * DM))[threadIdx.x] = o;
}

// ---------------- GEMM: C[M,N] = A[M,K] * W[N,K]^T (bf16 in, f32 acc) ----------------
template <int EPI>
__global__ __launch_bounds__(256) void gemm_bt(
    const u16* __restrict__ A, int lda,
    const u16* __restrict__ W,
    u16* __restrict__ Cb, float* __restrict__ Cf, int ldc,
    int M, int N, int K,
    const float* __restrict__ bias,
    const float* __restrict__ xres, const float* __restrict__ th,
    const float* __restrict__ sd) {
    __shared__ u16 As[128 * 32];
    __shared__ u16 Bs[128 * 32];
    const int tid = threadIdx.x;
    const int wave = tid >> 6, lane = tid & 63;
    const int bm = blockIdx.x, bn = blockIdx.y;
    const int srow = lane >> 2, scol = (lane & 3) * 8;
    const int wr = wave >> 1, wc = wave & 1;
    const int fl = lane & 15, fh = lane >> 4;

    f32x4 acc[4][4];
#pragma unroll
    for (int m = 0; m < 4; m++)
#pragma unroll
        for (int n = 0; n < 4; n++) acc[m][n] = f32x4{0.f, 0.f, 0.f, 0.f};

    int ra[2], rb[2];
    u16* ldsA[2]; u16* ldsB[2];
#pragma unroll
    for (int i = 0; i < 2; i++) {
        int r = (wave * 2 + i) * 16 + srow;
        ra[i] = min(bm * 128 + r, M - 1);
        rb[i] = min(bn * 128 + r, N - 1);
        ldsA[i] = As + (wave * 2 + i) * 512 + lane * 8;
        ldsB[i] = Bs + (wave * 2 + i) * 512 + lane * 8;
    }

    for (int k0 = 0; k0 < K; k0 += 32) {
        __syncthreads();
#pragma unroll
        for (int i = 0; i < 2; i++) {
            async16(ldsA[i], A + (size_t)ra[i] * lda + k0 + scol);
            async16(ldsB[i], W + (size_t)rb[i] * K + k0 + scol);
        }
        __syncthreads();
        s16x8 av[4], bv[4];
#pragma unroll
        for (int m = 0; m < 4; m++)
            av[m] = *(const s16x8*)(As + (wr * 64 + m * 16 + fl) * 32 + fh * 8);
#pragma unroll
        for (int n = 0; n < 4; n++)
            bv[n] = *(const s16x8*)(Bs + (wc * 64 + n * 16 + fl) * 32 + fh * 8);
#pragma unroll
        for (int m = 0; m < 4; m++)
#pragma unroll
            for (int n = 0; n < 4; n++)
                acc[m][n] = __builtin_amdgcn_mfma_f32_16x16x32_bf16(av[m], bv[n], acc[m][n], 0, 0, 0);
    }

#pragma unroll
    for (int m = 0; m < 4; m++) {
#pragma unroll
        for (int j = 0; j < 4; j++) {
            int row = bm * 128 + wr * 64 + m * 16 + fh * 4 + j;
            if (row >= M) continue;
#pragma unroll
            for (int n = 0; n < 4; n++) {
                int col = bn * 128 + wc * 64 + n * 16 + fl;
                if (col >= N) continue;
                float v = acc[m][n][j];
                size_t idx = (size_t)row * ldc + col;
                if (EPI == 0) {
                    Cb[idx] = f2bf(v);
                } else if (EPI == 1) {
                    Cb[idx] = f2bf(softplus_f(v + bias[col]));
                } else {
                    Cf[idx] = xres[idx] + v * expf(-sd[col] * th[row]);
                }
            }
        }
    }
}

// ---------------- x_proj split-K GEMM ----------------
__global__ __launch_bounds__(256) void xp_gemm(const u16* __restrict__ A,
                                               const u16* __restrict__ W,
                                               float* __restrict__ part) {
    __shared__ u16 As[128 * 64];
    __shared__ u16 Bs[XPN * 64];
    const int tid = threadIdx.x;
    const int wave = tid >> 6, lane = tid & 63;
    const int bm = blockIdx.x, sp = blockIdx.y;
    const int fl = lane & 15, fh = lane >> 4;
    const int trow = tid >> 3, tcol = (tid & 7) * 8;

    f32x4 acc[2][6];
#pragma unroll
    for (int m = 0; m < 2; m++)
#pragma unroll
        for (int n = 0; n < 6; n++) acc[m][n] = f32x4{0.f, 0.f, 0.f, 0.f};

    const int kbeg = sp * (DI / XP_SPLIT);
    for (int k0 = kbeg; k0 < kbeg + DI / XP_SPLIT; k0 += 64) {
        __syncthreads();
#pragma unroll
        for (int i = 0; i < 4; i++)
            async16(As + i * 2048 + tid * 8,
                    A + (size_t)(bm * 128 + i * 32 + trow) * DI + k0 + tcol);
#pragma unroll
        for (int i = 0; i < 3; i++)
            async16(Bs + i * 2048 + tid * 8,
                    W + (size_t)(i * 32 + trow) * DI + k0 + tcol);
        __syncthreads();
#pragma unroll
        for (int kk = 0; kk < 2; kk++) {
            s16x8 av[2], bv[6];
#pragma unroll
            for (int m = 0; m < 2; m++)
                av[m] = *(const s16x8*)(As + (wave * 32 + m * 16 + fl) * 64 + kk * 32 + fh * 8);
#pragma unroll
            for (int n = 0; n < 6; n++)
                bv[n] = *(const s16x8*)(Bs + (n * 16 + fl) * 64 + kk * 32 + fh * 8);
#pragma unroll
            for (int m = 0; m < 2; m++)
#pragma unroll
                for (int n = 0; n < 6; n++)
                    acc[m][n] = __builtin_amdgcn_mfma_f32_16x16x32_bf16(av[m], bv[n], acc[m][n], 0, 0, 0);
        }
    }
    float* dst = part + (size_t)sp * TOK * XPN;
#pragma unroll
    for (int m = 0; m < 2; m++)
#pragma unroll
        for (int j = 0; j < 4; j++) {
            int row = bm * 128 + wave * 32 + m * 16 + fh * 4 + j;
#pragma unroll
            for (int n = 0; n < 6; n++) {
                int col = n * 16 + fl;
                dst[(size_t)row * XPN + col] = acc[m][n][j];
            }
        }
}

__global__ __launch_bounds__(256) void xp_reduce(const float* __restrict__ part,
                                                 u16* __restrict__ out) {
    int i = blockIdx.x * 256 + threadIdx.x;
    if (i >= TOK * XPN) return;
    float s = 0.f;
#pragma unroll
    for (int sp = 0; sp < XP_SPLIT; sp++) s += part[(size_t)sp * TOK * XPN + i];
    out[i] = f2bf(s);
}

// ---------------- causal depthwise conv + silu (rolling window) ----------------
__global__ __launch_bounds__(256) void conv_silu_kernel(const u16* __restrict__ xz,
                                                        const float* __restrict__ cw,
                                                        const float* __restrict__ cb,
                                                        u16* __restrict__ u) {
    const int b = blockIdx.y;
    const int l0 = blockIdx.x * CONV_T;
    const int d0 = threadIdx.x * 8;
    float w0[8], w1[8], w2[8], w3[8], bias[8];
#pragma unroll
    for (int e = 0; e < 8; e++) {
        float4 wv = ((const float4*)cw)[d0 + e];
        w0[e] = wv.x; w1[e] = wv.y; w2[e] = wv.z; w3[e] = wv.w;
        bias[e] = cb[d0 + e];
    }
    float win[4][8];
#pragma unroll
    for (int i = 0; i < 3; i++) {
        int l = l0 - 3 + i;
        int slot = (l0 + 1 + i) & 3;
        if (l < 0) {
#pragma unroll
            for (int e = 0; e < 8; e++) win[slot][e] = 0.f;
        } else {
            u16x8 v = *(const u16x8*)(xz + ((size_t)(b * 2048 + l)) * (2 * DI) + d0);
#pragma unroll
            for (int e = 0; e < 8; e++) win[slot][e] = bf2f(v[e]);
        }
    }
#pragma unroll
    for (int t = 0; t < CONV_T; t++) {
        const int l = l0 + t;
        const size_t tok = (size_t)b * 2048 + l;
        u16x8 v = *(const u16x8*)(xz + tok * (2 * DI) + d0);
        const int s3 = t & 3;
#pragma unroll
        for (int e = 0; e < 8; e++) win[s3][e] = bf2f(v[e]);
        const int s0 = (t + 1) & 3, s1 = (t + 2) & 3, s2 = (t + 3) & 3;
        u16x8 o;
#pragma unroll
        for (int e = 0; e < 8; e++) {
            float a = bias[e];
            a = fmaf(w0[e], win[s0][e], a);
            a = fmaf(w1[e], win[s1][e], a);
            a = fmaf(w2[e], win[s2][e], a);
            a = fmaf(w3[e], win[s3][e], a);
            o[e] = f2bf(a / (1.f + expf(-a)));
        }
        *(u16x8*)(u + tok * DI + d0) = o;
    }
}

// ---------------- selective scan, chunked (NCHUNK=32, CH=64) ----------------
// pass A: per (c,b,d): local scan from h=0 -> qh[c][b][n][d], Sarr[c][b][d]
__global__ __launch_bounds__(256) void scan_passA(const u16* __restrict__ delta,
                                                  const u16* __restrict__ u,
                                                  const u16* __restrict__ xdbl,
                                                  const float* __restrict__ A_log,
                                                  float* __restrict__ qh,
                                                  float* __restrict__ Sarr) {
    const int d = blockIdx.x * 256 + threadIdx.x;
    const int b = blockIdx.y, c = blockIdx.z;
    float Av[16];
#pragma unroll
    for (int n = 0; n < 16; n++) Av[n] = -expf(A_log[d * 16 + n]);
    bool fast = true;
#pragma unroll
    for (int n = 0; n < 16; n++) fast = fast && (fabsf(Av[n] + (float)(n + 1)) < 1e-4f * (n + 1));
    const bool allfast = __all(fast);

    float h[16];
#pragma unroll
    for (int n = 0; n < 16; n++) h[n] = 0.f;
    float S = 0.f;
    const int l0 = c * CH;
    // pipeline prologue
    size_t tok = (size_t)b * 2048 + l0;
    float dt = bf2f(delta[tok * DI + d]);
    float uu = bf2f(u[tok * DI + d]);
    const uint4* bp0 = (const uint4*)(xdbl + tok * 96 + 64);
    uint4 b0 = bp0[0], b1 = bp0[1];
    for (int t = 0; t < CH; ++t) {
        // prefetch next token (clamped — last iter re-reads current)
        const int tn = (t + 1 < CH) ? t + 1 : t;
        const size_t tokn = (size_t)b * 2048 + l0 + tn;
        float dt_n = bf2f(delta[tokn * DI + d]);
        float uu_n = bf2f(u[tokn * DI + d]);
        const uint4* bpn = (const uint4*)(xdbl + tokn * 96 + 64);
        uint4 b0n = bpn[0], b1n = bpn[1];
        // compute current
        float du = dt * uu;
        float Bv[16];
        unpack8(b0, Bv); unpack8(b1, Bv + 8);
        float e[16];
        if (allfast) {
            float r = expf(-dt);
            e[0] = r;
#pragma unroll
            for (int n = 1; n < 16; n++) e[n] = e[n - 1] * r;
        } else {
#pragma unroll
            for (int n = 0; n < 16; n++) e[n] = expf(dt * Av[n]);
        }
#pragma unroll
        for (int n = 0; n < 16; n++) h[n] = fmaf(e[n], h[n], du * Bv[n]);
        S += dt;
        dt = dt_n; uu = uu_n; b0 = b0n; b1 = b1n;
    }
    const size_t base = ((size_t)(c * 4 + b) * 16) * DI + d;
#pragma unroll
    for (int n = 0; n < 16; n++) qh[base + (size_t)n * DI] = h[n];
    Sarr[(size_t)(c * 4 + b) * DI + d] = S;
}

// pass B: parallel over (b,n,d) chains; in-place qh: q[c] -> hin[c]
__global__ __launch_bounds__(256) void scan_passB(float* __restrict__ qh,
                                                  const float* __restrict__ Sarr,
                                                  const float* __restrict__ A_log) {
    const int idx = blockIdx.x * 256 + threadIdx.x;  // 4*16*2048 = 131072
    const int d = idx & (DI - 1);
    const int n = (idx >> 11) & 15;
    const int b = idx >> 15;
    const float Avn = -expf(A_log[d * 16 + n]);
    float h = 0.f;
    for (int c = 0; c < NCHUNK; c++) {
        const size_t base = ((size_t)(c * 4 + b) * 16 + n) * DI + d;
        const float qv = qh[base];
        const float S = Sarr[(size_t)(c * 4 + b) * DI + d];
        qh[base] = h;  // becomes hin for pass C
        h = fmaf(expf(Avn * S), h, qv);
    }
}

// pass C: replay with h0 = qh (hin), emit yg = (y + u*D) * silu(z)
__global__ __launch_bounds__(256) void scan_passC(const u16* __restrict__ delta,
                                                  const u16* __restrict__ u,
                                                  const u16* __restrict__ xdbl,
                                                  const u16* __restrict__ xz,
                                                  const float* __restrict__ A_log,
                                                  const float* __restrict__ Dvec,
                                                  const float* __restrict__ qh,
                                                  u16* __restrict__ yg) {
    const int d = blockIdx.x * 256 + threadIdx.x;
    const int b = blockIdx.y, c = blockIdx.z;
    float Av[16];
#pragma unroll
    for (int n = 0; n < 16; n++) Av[n] = -expf(A_log[d * 16 + n]);
    bool fast = true;
#pragma unroll
    for (int n = 0; n < 16; n++) fast = fast && (fabsf(Av[n] + (float)(n + 1)) < 1e-4f * (n + 1));
    const bool allfast = __all(fast);
    const float Dd = Dvec[d];

    float h[16];
    const size_t hbase = ((size_t)(c * 4 + b) * 16) * DI + d;
#pragma unroll
    for (int n = 0; n < 16; n++) h[n] = qh[hbase + (size_t)n * DI];

    const int l0 = c * CH;
    // pipeline prologue
    size_t tok = (size_t)b * 2048 + l0;
    float dt = bf2f(delta[tok * DI + d]);
    float uu = bf2f(u[tok * DI + d]);
    float zz = bf2f(xz[tok * (2 * DI) + DI + d]);
    const uint4* bp0 = (const uint4*)(xdbl + tok * 96 + 64);
    uint4 b0 = bp0[0], b1 = bp0[1], c0 = bp0[2], c1 = bp0[3];
    for (int t = 0; t < CH; ++t) {
        const int tn = (t + 1 < CH) ? t + 1 : t;
        const size_t tokn = (size_t)b * 2048 + l0 + tn;
        float dt_n = bf2f(delta[tokn * DI + d]);
        float uu_n = bf2f(u[tokn * DI + d]);
        float zz_n = bf2f(xz[tokn * (2 * DI) + DI + d]);
        const uint4* bpn = (const uint4*)(xdbl + tokn * 96 + 64);
        uint4 b0n = bpn[0], b1n = bpn[1], c0n = bpn[2], c1n = bpn[3];

        float du = dt * uu;
        float Bv[16], Cv[16];
        unpack8(b0, Bv); unpack8(b1, Bv + 8);
        unpack8(c0, Cv); unpack8(c1, Cv + 8);
        float e[16];
        if (allfast) {
            float r = expf(-dt);
            e[0] = r;
#pragma unroll
            for (int n = 1; n < 16; n++) e[n] = e[n - 1] * r;
        } else {
#pragma unroll
            for (int n = 0; n < 16; n++) e[n] = expf(dt * Av[n]);
        }
        float y = 0.f;
#pragma unroll
        for (int n = 0; n < 16; n++) {
            h[n] = fmaf(e[n], h[n], du * Bv[n]);
            y = fmaf(h[n], Cv[n], y);
        }
        float sz = zz / (1.f + expf(-zz));
        const size_t tokc = (size_t)b * 2048 + l0 + t;
        yg[tokc * DI + d] = f2bf((y + uu * Dd) * sz);

        dt = dt_n; uu = uu_n; zz = zz_n;
        b0 = b0n; b1 = b1n; c0 = c0n; c1 = c1n;
    }
}

// ---------------- host ----------------
extern "C" void kernel_launch(void* const* d_in, const int* in_sizes, int n_in,
                              void* d_out, int out_size, void* d_ws, size_t ws_size,
                              hipStream_t stream) {
    const float* x = (const float*)d_in[0];
    const float* tau = (const float*)d_in[1];
    const float* ln_g = (const float*)d_in[2];
    const float* ln_b = (const float*)d_in[3];
    const float* in_proj_w = (const float*)d_in[4];
    const float* conv_w = (const float*)d_in[5];
    const float* conv_b = (const float*)d_in[6];
    const float* x_proj_w = (const float*)d_in[7];
    const float* dt_proj_w = (const float*)d_in[8];
    const float* dt_proj_b = (const float*)d_in[9];
    const float* A_log = (const float*)d_in[10];
    const float* Dvec = (const float*)d_in[11];
    const float* out_proj_w = (const float*)d_in[12];
    const float* log_decay = (const float*)d_in[13];
    float* out = (float*)d_out;

    char* ws = (char*)d_ws;
    size_t off = 0;
    auto alloc = [&](size_t bytes) -> void* {
        void* p = ws + off;
        off += (bytes + 255) & ~(size_t)255;
        return p;
    };
    u16* xn    = (u16*)alloc((size_t)TOK * DM * 2);        // 16 MB (reused as xp_part)
    u16* w_in  = (u16*)alloc((size_t)2 * DI * DM * 2);     // 8 MB
    u16* w_xp  = (u16*)alloc((size_t)XPN * DI * 2);
    u16* w_dt  = (u16*)alloc((size_t)DI * DR * 2);
    u16* w_out = (u16*)alloc((size_t)DM * DI * 2);         // 4 MB
    u16* xz    = (u16*)alloc((size_t)TOK * 2 * DI * 2);    // 64 MB
    u16* u     = (u16*)alloc((size_t)TOK * DI * 2);        // 32 MB
    u16* xdbl  = (u16*)alloc((size_t)TOK * XPN * 2);       // 1.5 MB
    u16* delta = (u16*)alloc((size_t)TOK * DI * 2);        // 32 MB
    float* qh   = (float*)alloc((size_t)NCHUNK * 4 * 16 * DI * 4);  // 16 MB
    float* Sarr = (float*)alloc((size_t)NCHUNK * 4 * DI * 4);       // 1 MB
    u16* yg    = (u16*)alloc((size_t)TOK * DI * 2);        // 32 MB
    float* th = (float*)alloc((size_t)TOK * 4);
    float* sd = (float*)alloc((size_t)DM * 4);
    float* xp_part = (float*)xn;  // overlay: xn dead after in_proj

    // weights -> bf16
    cvt_kernel<<<4096, 256, 0, stream>>>(in_proj_w, w_in, (2 * DI * DM) / 4);
    cvt_kernel<<<192, 256, 0, stream>>>(x_proj_w, w_xp, (XPN * DI) / 4);
    cvt_kernel<<<128, 256, 0, stream>>>(dt_proj_w, w_dt, (DI * DR) / 4);
    cvt_kernel<<<2048, 256, 0, stream>>>(out_proj_w, w_out, (DM * DI) / 4);
    prep_kernel<<<32, 256, 0, stream>>>(tau, log_decay, th, sd);

    // LN
    ln_kernel<<<TOK, 256, 0, stream>>>(x, ln_g, ln_b, xn);

    // in_proj: [8192,1024] x [4096,1024]^T -> xz bf16 [8192,4096]
    gemm_bt<0><<<dim3(64, 32), 256, 0, stream>>>(xn, DM, w_in, xz, nullptr, 2 * DI,
                                                 TOK, 2 * DI, DM, nullptr, nullptr, nullptr, nullptr);
    // conv + silu -> u bf16 [8192,2048]
    conv_silu_kernel<<<dim3(2048 / CONV_T, 4), 256, 0, stream>>>(xz, conv_w, conv_b, u);

    // x_proj split-K: [8192,2048] x [96,2048]^T
    xp_gemm<<<dim3(64, XP_SPLIT), 256, 0, stream>>>(u, w_xp, xp_part);
    xp_reduce<<<(TOK * XPN + 255) / 256, 256, 0, stream>>>(xp_part, xdbl);

    // dt_proj + softplus: [8192,64] x [2048,64]^T -> delta bf16 [8192,2048]
    gemm_bt<1><<<dim3(64, 16), 256, 0, stream>>>(xdbl, XPN, w_dt, delta, nullptr, DI,
                                                 TOK, DI, DR, dt_proj_b, nullptr, nullptr, nullptr);

    // chunked selective scan
    scan_passA<<<dim3(8, 4, NCHUNK), 256, 0, stream>>>(delta, u, xdbl, A_log, qh, Sarr);
    scan_passB<<<512, 256, 0, stream>>>(qh, Sarr, A_log);
    scan_passC<<<dim3(8, 4, NCHUNK), 256, 0, stream>>>(delta, u, xdbl, xz, A_log, Dvec, qh, yg);

    // out_proj + gate + residual: [8192,2048] x [1024,2048]^T -> out f32 [8192,1024]
    gemm_bt<2><<<dim3(64, 8), 256, 0, stream>>>(yg, DI, w_out, nullptr, out, DM,
                                                TOK, DM, DI, nullptr, x, th, sd);
}

// Round 4
// 379.991 us; speedup vs baseline: 1.7027x; 1.1015x over previous
//
#include <hip/hip_runtime.h>

typedef unsigned short u16;
typedef unsigned int u32;
typedef short s16x8 __attribute__((ext_vector_type(8)));
typedef u16 u16x8 __attribute__((ext_vector_type(8)));
typedef float f32x4 __attribute__((ext_vector_type(4)));

#define TOK 8192
#define DM 1024
#define DI 2048
#define DS 16
#define DR 64
#define NCHUNK 32
#define CH 64
#define XPN 96
#define XP_SPLIT 4
#define CONV_T 16

#define SBAR() do { asm volatile("" ::: "memory"); __builtin_amdgcn_s_barrier(); asm volatile("" ::: "memory"); } while (0)
#define WAITVM(N) do { asm volatile("s_waitcnt vmcnt(" #N ")" ::: "memory"); __builtin_amdgcn_sched_barrier(0); } while (0)
#define WAITLGKM0() do { asm volatile("s_waitcnt lgkmcnt(0)" ::: "memory"); __builtin_amdgcn_sched_barrier(0); } while (0)

__device__ __forceinline__ u16 f2bf(float f) {
    u32 u = __float_as_uint(f);
    u32 r = (u + 0x7fffu + ((u >> 16) & 1u)) >> 16;
    return (u16)r;
}
__device__ __forceinline__ float bf2f(u16 h) {
    return __uint_as_float(((u32)h) << 16);
}
__device__ __forceinline__ float softplus_f(float x) {
    return (x > 15.f) ? x : log1pf(expf(x));
}
__device__ __forceinline__ void unpack8(const uint4 v, float* o) {
    o[0] = __uint_as_float(v.x << 16); o[1] = __uint_as_float(v.x & 0xffff0000u);
    o[2] = __uint_as_float(v.y << 16); o[3] = __uint_as_float(v.y & 0xffff0000u);
    o[4] = __uint_as_float(v.z << 16); o[5] = __uint_as_float(v.z & 0xffff0000u);
    o[6] = __uint_as_float(v.w << 16); o[7] = __uint_as_float(v.w & 0xffff0000u);
}
__device__ __forceinline__ void async16(u16* lds, const u16* g) {
    __builtin_amdgcn_global_load_lds(
        (const __attribute__((address_space(1))) void*)g,
        (__attribute__((address_space(3))) void*)lds, 16, 0, 0);
}

// ---------------- weight f32 -> bf16 ----------------
__global__ __launch_bounds__(256) void cvt_kernel(const float* __restrict__ src,
                                                  u16* __restrict__ dst, int n4) {
    int i = blockIdx.x * 256 + threadIdx.x;
    if (i >= n4) return;
    float4 v = ((const float4*)src)[i];
    ushort4 o;
    o.x = f2bf(v.x); o.y = f2bf(v.y); o.z = f2bf(v.z); o.w = f2bf(v.w);
    ((ushort4*)dst)[i] = o;
}

// ---------------- th[m], sd[n] ----------------
__global__ __launch_bounds__(256) void prep_kernel(const float* __restrict__ tau,
                                                   const float* __restrict__ log_decay,
                                                   float* __restrict__ th,
                                                   float* __restrict__ sd) {
    int i = blockIdx.x * 256 + threadIdx.x;
    if (i < TOK) th[i] = fmaxf(tau[i] * (1.f / 3600.f), 1e-4f);
    if (i < DM)  sd[i] = softplus_f(log_decay[i]);
}

// ---------------- LayerNorm -> bf16 ----------------
__global__ __launch_bounds__(256) void ln_kernel(const float* __restrict__ x,
                                                 const float* __restrict__ g,
                                                 const float* __restrict__ bb,
                                                 u16* __restrict__ xn) {
    const int tok = blockIdx.x;
    const float4 v = ((const float4*)(x + (size_t)tok * DM))[threadIdx.x];
    float s = v.x + v.y + v.z + v.w;
    float sq = v.x * v.x + v.y * v.y + v.z * v.z + v.w * v.w;
#pragma unroll
    for (int off = 32; off; off >>= 1) {
        s += __shfl_xor(s, off);
        sq += __shfl_xor(sq, off);
    }
    __shared__ float red[8];
    const int wv = threadIdx.x >> 6;
    if ((threadIdx.x & 63) == 0) { red[wv] = s; red[4 + wv] = sq; }
    __syncthreads();
    s = red[0] + red[1] + red[2] + red[3];
    sq = red[4] + red[5] + red[6] + red[7];
    const float mean = s * (1.f / DM);
    const float var = sq * (1.f / DM) - mean * mean;
    const float rstd = rsqrtf(var + 1e-5f);
    const float4 gv = ((const float4*)g)[threadIdx.x];
    const float4 bv = ((const float4*)bb)[threadIdx.x];
    ushort4 o;
    o.x = f2bf((v.x - mean) * rstd * gv.x + bv.x);
    o.y = f2bf((v.y - mean) * rstd * gv.y + bv.y);
    o.z = f2bf((v.z - mean) * rstd * gv.z + bv.z);
    o.w = f2bf((v.w - mean) * rstd * gv.w + bv.w);
    ((ushort4*)(xn + (size_t)tok * DM))[threadIdx.x] = o;
}

// ================= deep-pipelined GEMM (BM=256,BN=128,BK=64, 8 waves) =================
// C[M,N] = A[M,K] * W[N,K]^T.  Requires 256|M, 128|N, 64|K, K>=192.
// Triple-buffered LDS (144KB), staging 2 K-tiles ahead, counted vmcnt(6),
// XOR slot swizzle (slot ^= row&7) on both stage-source and ds_read.
// EPI 0: bf16 store.  EPI 2: f32 out = xres + acc*exp(-sd[col]*th[row]).
template <int EPI>
__global__ __launch_bounds__(512, 2) void gemm8(
    const u16* __restrict__ A, int lda,
    const u16* __restrict__ W,
    u16* __restrict__ Cb, float* __restrict__ Cf, int ldc,
    int M, int N, int K,
    const float* __restrict__ xres, const float* __restrict__ th,
    const float* __restrict__ sd) {
    __shared__ __align__(16) u16 lds[3 * 24576];  // 3 x (A 16384 + B 8192) elems = 144 KB
    const int tid = threadIdx.x;
    const int wave = tid >> 6, lane = tid & 63;
    const int wm = wave >> 1, wn = wave & 1;
    const int fl = lane & 15, fh = lane >> 4;
    const int bm = blockIdx.x, bn = blockIdx.y;
    const int NT = K >> 6;

    // stage cursors (pre-swizzled global source; linear LDS dest = uniform + lane*16B)
    const int srow = tid >> 3;                       // 0..63
    const int sphys = tid & 7;
    const int scol = (sphys ^ (srow & 7)) << 3;      // element col within BK=64
    const u16* pA = A + (size_t)(bm * 256 + srow) * lda + scol;
    const u16* pB = W + (size_t)(bn * 128 + srow) * K + scol;
    const u32 doff = (u32)srow * 128u + ((u32)sphys << 4);  // byte offset within buffer

    f32x4 acc[4][4];
#pragma unroll
    for (int m = 0; m < 4; m++)
#pragma unroll
        for (int n = 0; n < 4; n++) acc[m][n] = f32x4{0.f, 0.f, 0.f, 0.f};

    auto stageA3 = [&](int buf) {  // A rows 0..191 of tile (3 loads)
        char* base = (char*)(lds + buf * 24576);
#pragma unroll
        for (int j = 0; j < 3; j++)
            async16((u16*)(base + doff + j * 8192), pA + (size_t)j * 64 * lda);
    };
    auto stageA1B2 = [&](int buf) {  // A rows 192..255 + B rows 0..127 (3 loads)
        char* base = (char*)(lds + buf * 24576);
        async16((u16*)(base + doff + 3 * 8192), pA + (size_t)3 * 64 * lda);
        char* bbase = (char*)(lds + buf * 24576 + 16384);
#pragma unroll
        for (int j = 0; j < 2; j++)
            async16((u16*)(bbase + doff + j * 8192), pB + (size_t)j * 64 * K);
    };
    auto ldA = [&](int buf, int m, int kk) -> s16x8 {
        int r = wm * 64 + m * 16 + fl;
        u32 byte = (u32)r * 128u + (u32)((((kk << 2) | fh) ^ (r & 7)) << 4);
        return *(const s16x8*)((const char*)(lds + buf * 24576) + byte);
    };
    auto ldB = [&](int buf, int n, int kk) -> s16x8 {
        int r = wn * 64 + n * 16 + fl;
        u32 byte = (u32)r * 128u + (u32)((((kk << 2) | fh) ^ (r & 7)) << 4);
        return *(const s16x8*)((const char*)(lds + buf * 24576 + 16384) + byte);
    };

    // prologue: stage tiles 0 and 1
    stageA3(0); stageA1B2(0); pA += 64; pB += 64;
    stageA3(1); stageA1B2(1); pA += 64; pB += 64;
    WAITVM(6);           // tile-0 loads landed (tile-1's 6 stay in flight)
    SBAR();

    int cur = 0, nxt2 = 2;
    for (int t = 0; t < NT; ++t) {
        const bool st = (t + 2 < NT);
        // ---------- phase A: n-frags 0,1 ----------
        s16x8 ah[4][2], bh[2][2];
#pragma unroll
        for (int m = 0; m < 4; m++) { ah[m][0] = ldA(cur, m, 0); ah[m][1] = ldA(cur, m, 1); }
#pragma unroll
        for (int n = 0; n < 2; n++) { bh[n][0] = ldB(cur, n, 0); bh[n][1] = ldB(cur, n, 1); }
        if (st) stageA3(nxt2);
        SBAR();
        __builtin_amdgcn_s_setprio(1);
#pragma unroll
        for (int kk = 0; kk < 2; kk++)
#pragma unroll
            for (int m = 0; m < 4; m++)
#pragma unroll
                for (int n = 0; n < 2; n++)
                    acc[m][n] = __builtin_amdgcn_mfma_f32_16x16x32_bf16(ah[m][kk], bh[n][kk], acc[m][n], 0, 0, 0);
        __builtin_amdgcn_s_setprio(0);
        __builtin_amdgcn_sched_barrier(0);
        SBAR();
        // ---------- phase B: n-frags 2,3 ----------
#pragma unroll
        for (int n = 0; n < 2; n++) { bh[n][0] = ldB(cur, n + 2, 0); bh[n][1] = ldB(cur, n + 2, 1); }
        if (st) { stageA1B2(nxt2); pA += 64; pB += 64; }
        SBAR();
        __builtin_amdgcn_s_setprio(1);
#pragma unroll
        for (int kk = 0; kk < 2; kk++)
#pragma unroll
            for (int m = 0; m < 4; m++)
#pragma unroll
                for (int n = 0; n < 2; n++)
                    acc[m][n + 2] = __builtin_amdgcn_mfma_f32_16x16x32_bf16(ah[m][kk], bh[n][kk], acc[m][n + 2], 0, 0, 0);
        __builtin_amdgcn_s_setprio(0);
        __builtin_amdgcn_sched_barrier(0);
        if (t + 1 < NT) {
            WAITLGKM0();            // all my LDS reads of cur serviced before anyone overwrites
            if (st) { WAITVM(6); } else { WAITVM(0); }  // certify tile t+1's loads landed
            SBAR();
        }
        cur = (cur == 2) ? 0 : cur + 1;
        nxt2 = (nxt2 == 2) ? 0 : nxt2 + 1;
    }

    // epilogue
#pragma unroll
    for (int m = 0; m < 4; m++)
#pragma unroll
        for (int j = 0; j < 4; j++) {
            int row = bm * 256 + wm * 64 + m * 16 + fh * 4 + j;
#pragma unroll
            for (int n = 0; n < 4; n++) {
                int col = bn * 128 + wn * 64 + n * 16 + fl;
                float v = acc[m][n][j];
                size_t idx = (size_t)row * ldc + col;
                if (EPI == 0) {
                    Cb[idx] = f2bf(v);
                } else {
                    Cf[idx] = xres[idx] + v * expf(-sd[col] * th[row]);
                }
            }
        }
}

// ---------------- small GEMM (dt_proj): C[M,N] = A[M,K] * W[N,K]^T ----------------
// EPI 1: softplus(acc+bias[col]) -> bf16
template <int EPI>
__global__ __launch_bounds__(256) void gemm_bt(
    const u16* __restrict__ A, int lda,
    const u16* __restrict__ W,
    u16* __restrict__ Cb, float* __restrict__ Cf, int ldc,
    int M, int N, int K,
    const float* __restrict__ bias,
    const float* __restrict__ xres, const float* __restrict__ th,
    const float* __restrict__ sd) {
    __shared__ u16 As[128 * 32];
    __shared__ u16 Bs[128 * 32];
    const int tid = threadIdx.x;
    const int wave = tid >> 6, lane = tid & 63;
    const int bm = blockIdx.x, bn = blockIdx.y;
    const int srow = lane >> 2, scol = (lane & 3) * 8;
    const int wr = wave >> 1, wc = wave & 1;
    const int fl = lane & 15, fh = lane >> 4;

    f32x4 acc[4][4];
#pragma unroll
    for (int m = 0; m < 4; m++)
#pragma unroll
        for (int n = 0; n < 4; n++) acc[m][n] = f32x4{0.f, 0.f, 0.f, 0.f};

    int ra[2], rb[2];
    u16* ldsA[2]; u16* ldsB[2];
#pragma unroll
    for (int i = 0; i < 2; i++) {
        int r = (wave * 2 + i) * 16 + srow;
        ra[i] = min(bm * 128 + r, M - 1);
        rb[i] = min(bn * 128 + r, N - 1);
        ldsA[i] = As + (wave * 2 + i) * 512 + lane * 8;
        ldsB[i] = Bs + (wave * 2 + i) * 512 + lane * 8;
    }

    for (int k0 = 0; k0 < K; k0 += 32) {
        __syncthreads();
#pragma unroll
        for (int i = 0; i < 2; i++) {
            async16(ldsA[i], A + (size_t)ra[i] * lda + k0 + scol);
            async16(ldsB[i], W + (size_t)rb[i] * K + k0 + scol);
        }
        __syncthreads();
        s16x8 av[4], bv[4];
#pragma unroll
        for (int m = 0; m < 4; m++)
            av[m] = *(const s16x8*)(As + (wr * 64 + m * 16 + fl) * 32 + fh * 8);
#pragma unroll
        for (int n = 0; n < 4; n++)
            bv[n] = *(const s16x8*)(Bs + (wc * 64 + n * 16 + fl) * 32 + fh * 8);
#pragma unroll
        for (int m = 0; m < 4; m++)
#pragma unroll
            for (int n = 0; n < 4; n++)
                acc[m][n] = __builtin_amdgcn_mfma_f32_16x16x32_bf16(av[m], bv[n], acc[m][n], 0, 0, 0);
    }

#pragma unroll
    for (int m = 0; m < 4; m++) {
#pragma unroll
        for (int j = 0; j < 4; j++) {
            int row = bm * 128 + wr * 64 + m * 16 + fh * 4 + j;
            if (row >= M) continue;
#pragma unroll
            for (int n = 0; n < 4; n++) {
                int col = bn * 128 + wc * 64 + n * 16 + fl;
                if (col >= N) continue;
                float v = acc[m][n][j];
                size_t idx = (size_t)row * ldc + col;
                if (EPI == 0) {
                    Cb[idx] = f2bf(v);
                } else if (EPI == 1) {
                    Cb[idx] = f2bf(softplus_f(v + bias[col]));
                } else {
                    Cf[idx] = xres[idx] + v * expf(-sd[col] * th[row]);
                }
            }
        }
    }
}

// ---------------- x_proj split-K GEMM ----------------
__global__ __launch_bounds__(256) void xp_gemm(const u16* __restrict__ A,
                                               const u16* __restrict__ W,
                                               float* __restrict__ part) {
    __shared__ u16 As[128 * 64];
    __shared__ u16 Bs[XPN * 64];
    const int tid = threadIdx.x;
    const int wave = tid >> 6, lane = tid & 63;
    const int bm = blockIdx.x, sp = blockIdx.y;
    const int fl = lane & 15, fh = lane >> 4;
    const int trow = tid >> 3, tcol = (tid & 7) * 8;

    f32x4 acc[2][6];
#pragma unroll
    for (int m = 0; m < 2; m++)
#pragma unroll
        for (int n = 0; n < 6; n++) acc[m][n] = f32x4{0.f, 0.f, 0.f, 0.f};

    const int kbeg = sp * (DI / XP_SPLIT);
    for (int k0 = kbeg; k0 < kbeg + DI / XP_SPLIT; k0 += 64) {
        __syncthreads();
#pragma unroll
        for (int i = 0; i < 4; i++)
            async16(As + i * 2048 + tid * 8,
                    A + (size_t)(bm * 128 + i * 32 + trow) * DI + k0 + tcol);
#pragma unroll
        for (int i = 0; i < 3; i++)
            async16(Bs + i * 2048 + tid * 8,
                    W + (size_t)(i * 32 + trow) * DI + k0 + tcol);
        __syncthreads();
#pragma unroll
        for (int kk = 0; kk < 2; kk++) {
            s16x8 av[2], bv[6];
#pragma unroll
            for (int m = 0; m < 2; m++)
                av[m] = *(const s16x8*)(As + (wave * 32 + m * 16 + fl) * 64 + kk * 32 + fh * 8);
#pragma unroll
            for (int n = 0; n < 6; n++)
                bv[n] = *(const s16x8*)(Bs + (n * 16 + fl) * 64 + kk * 32 + fh * 8);
#pragma unroll
            for (int m = 0; m < 2; m++)
#pragma unroll
                for (int n = 0; n < 6; n++)
                    acc[m][n] = __builtin_amdgcn_mfma_f32_16x16x32_bf16(av[m], bv[n], acc[m][n], 0, 0, 0);
        }
    }
    float* dst = part + (size_t)sp * TOK * XPN;
#pragma unroll
    for (int m = 0; m < 2; m++)
#pragma unroll
        for (int j = 0; j < 4; j++) {
            int row = bm * 128 + wave * 32 + m * 16 + fh * 4 + j;
#pragma unroll
            for (int n = 0; n < 6; n++) {
                int col = n * 16 + fl;
                dst[(size_t)row * XPN + col] = acc[m][n][j];
            }
        }
}

__global__ __launch_bounds__(256) void xp_reduce(const float* __restrict__ part,
                                                 u16* __restrict__ out) {
    int i = blockIdx.x * 256 + threadIdx.x;
    if (i >= TOK * XPN) return;
    float s = 0.f;
#pragma unroll
    for (int sp = 0; sp < XP_SPLIT; sp++) s += part[(size_t)sp * TOK * XPN + i];
    out[i] = f2bf(s);
}

// ---------------- causal depthwise conv + silu (rolling window) ----------------
__global__ __launch_bounds__(256) void conv_silu_kernel(const u16* __restrict__ xz,
                                                        const float* __restrict__ cw,
                                                        const float* __restrict__ cb,
                                                        u16* __restrict__ u) {
    const int b = blockIdx.y;
    const int l0 = blockIdx.x * CONV_T;
    const int d0 = threadIdx.x * 8;
    float w0[8], w1[8], w2[8], w3[8], bias[8];
#pragma unroll
    for (int e = 0; e < 8; e++) {
        float4 wv = ((const float4*)cw)[d0 + e];
        w0[e] = wv.x; w1[e] = wv.y; w2[e] = wv.z; w3[e] = wv.w;
        bias[e] = cb[d0 + e];
    }
    float win[4][8];
#pragma unroll
    for (int i = 0; i < 3; i++) {
        int l = l0 - 3 + i;
        int slot = (l0 + 1 + i) & 3;
        if (l < 0) {
#pragma unroll
            for (int e = 0; e < 8; e++) win[slot][e] = 0.f;
        } else {
            u16x8 v = *(const u16x8*)(xz + ((size_t)(b * 2048 + l)) * (2 * DI) + d0);
#pragma unroll
            for (int e = 0; e < 8; e++) win[slot][e] = bf2f(v[e]);
        }
    }
#pragma unroll
    for (int t = 0; t < CONV_T; t++) {
        const int l = l0 + t;
        const size_t tok = (size_t)b * 2048 + l;
        u16x8 v = *(const u16x8*)(xz + tok * (2 * DI) + d0);
        const int s3 = t & 3;
#pragma unroll
        for (int e = 0; e < 8; e++) win[s3][e] = bf2f(v[e]);
        const int s0 = (t + 1) & 3, s1 = (t + 2) & 3, s2 = (t + 3) & 3;
        u16x8 o;
#pragma unroll
        for (int e = 0; e < 8; e++) {
            float a = bias[e];
            a = fmaf(w0[e], win[s0][e], a);
            a = fmaf(w1[e], win[s1][e], a);
            a = fmaf(w2[e], win[s2][e], a);
            a = fmaf(w3[e], win[s3][e], a);
            o[e] = f2bf(a / (1.f + expf(-a)));
        }
        *(u16x8*)(u + tok * DI + d0) = o;
    }
}

// ---------------- selective scan, chunked (NCHUNK=32, CH=64) ----------------
__global__ __launch_bounds__(256) void scan_passA(const u16* __restrict__ delta,
                                                  const u16* __restrict__ u,
                                                  const u16* __restrict__ xdbl,
                                                  const float* __restrict__ A_log,
                                                  float* __restrict__ qh,
                                                  float* __restrict__ Sarr) {
    const int d = blockIdx.x * 256 + threadIdx.x;
    const int b = blockIdx.y, c = blockIdx.z;
    float Av[16];
#pragma unroll
    for (int n = 0; n < 16; n++) Av[n] = -expf(A_log[d * 16 + n]);
    bool fast = true;
#pragma unroll
    for (int n = 0; n < 16; n++) fast = fast && (fabsf(Av[n] + (float)(n + 1)) < 1e-4f * (n + 1));
    const bool allfast = __all(fast);

    float h[16];
#pragma unroll
    for (int n = 0; n < 16; n++) h[n] = 0.f;
    float S = 0.f;
    const int l0 = c * CH;
    size_t tok = (size_t)b * 2048 + l0;
    float dt = bf2f(delta[tok * DI + d]);
    float uu = bf2f(u[tok * DI + d]);
    const uint4* bp0 = (const uint4*)(xdbl + tok * 96 + 64);
    uint4 b0 = bp0[0], b1 = bp0[1];
    for (int t = 0; t < CH; ++t) {
        const int tn = (t + 1 < CH) ? t + 1 : t;
        const size_t tokn = (size_t)b * 2048 + l0 + tn;
        float dt_n = bf2f(delta[tokn * DI + d]);
        float uu_n = bf2f(u[tokn * DI + d]);
        const uint4* bpn = (const uint4*)(xdbl + tokn * 96 + 64);
        uint4 b0n = bpn[0], b1n = bpn[1];
        float du = dt * uu;
        float Bv[16];
        unpack8(b0, Bv); unpack8(b1, Bv + 8);
        float e[16];
        if (allfast) {
            float r = expf(-dt);
            e[0] = r;
#pragma unroll
            for (int n = 1; n < 16; n++) e[n] = e[n - 1] * r;
        } else {
#pragma unroll
            for (int n = 0; n < 16; n++) e[n] = expf(dt * Av[n]);
        }
#pragma unroll
        for (int n = 0; n < 16; n++) h[n] = fmaf(e[n], h[n], du * Bv[n]);
        S += dt;
        dt = dt_n; uu = uu_n; b0 = b0n; b1 = b1n;
    }
    const size_t base = ((size_t)(c * 4 + b) * 16) * DI + d;
#pragma unroll
    for (int n = 0; n < 16; n++) qh[base + (size_t)n * DI] = h[n];
    Sarr[(size_t)(c * 4 + b) * DI + d] = S;
}

__global__ __launch_bounds__(256) void scan_passB(float* __restrict__ qh,
                                                  const float* __restrict__ Sarr,
                                                  const float* __restrict__ A_log) {
    const int idx = blockIdx.x * 256 + threadIdx.x;
    const int d = idx & (DI - 1);
    const int n = (idx >> 11) & 15;
    const int b = idx >> 15;
    const float Avn = -expf(A_log[d * 16 + n]);
    float h = 0.f;
    for (int c = 0; c < NCHUNK; c++) {
        const size_t base = ((size_t)(c * 4 + b) * 16 + n) * DI + d;
        const float qv = qh[base];
        const float S = Sarr[(size_t)(c * 4 + b) * DI + d];
        qh[base] = h;
        h = fmaf(expf(Avn * S), h, qv);
    }
}

__global__ __launch_bounds__(256) void scan_passC(const u16* __restrict__ delta,
                                                  const u16* __restrict__ u,
                                                  const u16* __restrict__ xdbl,
                                                  const u16* __restrict__ xz,
                                                  const float* __restrict__ A_log,
                                                  const float* __restrict__ Dvec,
                                                  const float* __restrict__ qh,
                                                  u16* __restrict__ yg) {
    const int d = blockIdx.x * 256 + threadIdx.x;
    const int b = blockIdx.y, c = blockIdx.z;
    float Av[16];
#pragma unroll
    for (int n = 0; n < 16; n++) Av[n] = -expf(A_log[d * 16 + n]);
    bool fast = true;
#pragma unroll
    for (int n = 0; n < 16; n++) fast = fast && (fabsf(Av[n] + (float)(n + 1)) < 1e-4f * (n + 1));
    const bool allfast = __all(fast);
    const float Dd = Dvec[d];

    float h[16];
    const size_t hbase = ((size_t)(c * 4 + b) * 16) * DI + d;
#pragma unroll
    for (int n = 0; n < 16; n++) h[n] = qh[hbase + (size_t)n * DI];

    const int l0 = c * CH;
    size_t tok = (size_t)b * 2048 + l0;
    float dt = bf2f(delta[tok * DI + d]);
    float uu = bf2f(u[tok * DI + d]);
    float zz = bf2f(xz[tok * (2 * DI) + DI + d]);
    const uint4* bp0 = (const uint4*)(xdbl + tok * 96 + 64);
    uint4 b0 = bp0[0], b1 = bp0[1], c0 = bp0[2], c1 = bp0[3];
    for (int t = 0; t < CH; ++t) {
        const int tn = (t + 1 < CH) ? t + 1 : t;
        const size_t tokn = (size_t)b * 2048 + l0 + tn;
        float dt_n = bf2f(delta[tokn * DI + d]);
        float uu_n = bf2f(u[tokn * DI + d]);
        float zz_n = bf2f(xz[tokn * (2 * DI) + DI + d]);
        const uint4* bpn = (const uint4*)(xdbl + tokn * 96 + 64);
        uint4 b0n = bpn[0], b1n = bpn[1], c0n = bpn[2], c1n = bpn[3];

        float du = dt * uu;
        float Bv[16], Cv[16];
        unpack8(b0, Bv); unpack8(b1, Bv + 8);
        unpack8(c0, Cv); unpack8(c1, Cv + 8);
        float e[16];
        if (allfast) {
            float r = expf(-dt);
            e[0] = r;
#pragma unroll
            for (int n = 1; n < 16; n++) e[n] = e[n - 1] * r;
        } else {
#pragma unroll
            for (int n = 0; n < 16; n++) e[n] = expf(dt * Av[n]);
        }
        float y = 0.f;
#pragma unroll
        for (int n = 0; n < 16; n++) {
            h[n] = fmaf(e[n], h[n], du * Bv[n]);
            y = fmaf(h[n], Cv[n], y);
        }
        float sz = zz / (1.f + expf(-zz));
        const size_t tokc = (size_t)b * 2048 + l0 + t;
        yg[tokc * DI + d] = f2bf((y + uu * Dd) * sz);

        dt = dt_n; uu = uu_n; zz = zz_n;
        b0 = b0n; b1 = b1n; c0 = c0n; c1 = c1n;
    }
}

// ---------------- host ----------------
extern "C" void kernel_launch(void* const* d_in, const int* in_sizes, int n_in,
                              void* d_out, int out_size, void* d_ws, size_t ws_size,
                              hipStream_t stream) {
    const float* x = (const float*)d_in[0];
    const float* tau = (const float*)d_in[1];
    const float* ln_g = (const float*)d_in[2];
    const float* ln_b = (const float*)d_in[3];
    const float* in_proj_w = (const float*)d_in[4];
    const float* conv_w = (const float*)d_in[5];
    const float* conv_b = (const float*)d_in[6];
    const float* x_proj_w = (const float*)d_in[7];
    const float* dt_proj_w = (const float*)d_in[8];
    const float* dt_proj_b = (const float*)d_in[9];
    const float* A_log = (const float*)d_in[10];
    const float* Dvec = (const float*)d_in[11];
    const float* out_proj_w = (const float*)d_in[12];
    const float* log_decay = (const float*)d_in[13];
    float* out = (float*)d_out;

    char* ws = (char*)d_ws;
    size_t off = 0;
    auto alloc = [&](size_t bytes) -> void* {
        void* p = ws + off;
        off += (bytes + 255) & ~(size_t)255;
        return p;
    };
    u16* xn    = (u16*)alloc((size_t)TOK * DM * 2);        // 16 MB (reused as xp_part)
    u16* w_in  = (u16*)alloc((size_t)2 * DI * DM * 2);     // 8 MB
    u16* w_xp  = (u16*)alloc((size_t)XPN * DI * 2);
    u16* w_dt  = (u16*)alloc((size_t)DI * DR * 2);
    u16* w_out = (u16*)alloc((size_t)DM * DI * 2);         // 4 MB
    u16* xz    = (u16*)alloc((size_t)TOK * 2 * DI * 2);    // 64 MB
    u16* u     = (u16*)alloc((size_t)TOK * DI * 2);        // 32 MB
    u16* xdbl  = (u16*)alloc((size_t)TOK * XPN * 2);       // 1.5 MB
    u16* delta = (u16*)alloc((size_t)TOK * DI * 2);        // 32 MB
    float* qh   = (float*)alloc((size_t)NCHUNK * 4 * 16 * DI * 4);  // 16 MB
    float* Sarr = (float*)alloc((size_t)NCHUNK * 4 * DI * 4);       // 1 MB
    u16* yg    = (u16*)alloc((size_t)TOK * DI * 2);        // 32 MB
    float* th = (float*)alloc((size_t)TOK * 4);
    float* sd = (float*)alloc((size_t)DM * 4);
    float* xp_part = (float*)xn;  // overlay: xn dead after in_proj

    // weights -> bf16
    cvt_kernel<<<4096, 256, 0, stream>>>(in_proj_w, w_in, (2 * DI * DM) / 4);
    cvt_kernel<<<192, 256, 0, stream>>>(x_proj_w, w_xp, (XPN * DI) / 4);
    cvt_kernel<<<128, 256, 0, stream>>>(dt_proj_w, w_dt, (DI * DR) / 4);
    cvt_kernel<<<2048, 256, 0, stream>>>(out_proj_w, w_out, (DM * DI) / 4);
    prep_kernel<<<32, 256, 0, stream>>>(tau, log_decay, th, sd);

    // LN
    ln_kernel<<<TOK, 256, 0, stream>>>(x, ln_g, ln_b, xn);

    // in_proj: [8192,1024] x [4096,1024]^T -> xz bf16 [8192,4096]
    gemm8<0><<<dim3(32, 32), 512, 0, stream>>>(xn, DM, w_in, xz, nullptr, 2 * DI,
                                               TOK, 2 * DI, DM, nullptr, nullptr, nullptr);
    // conv + silu -> u bf16 [8192,2048]
    conv_silu_kernel<<<dim3(2048 / CONV_T, 4), 256, 0, stream>>>(xz, conv_w, conv_b, u);

    // x_proj split-K: [8192,2048] x [96,2048]^T
    xp_gemm<<<dim3(64, XP_SPLIT), 256, 0, stream>>>(u, w_xp, xp_part);
    xp_reduce<<<(TOK * XPN + 255) / 256, 256, 0, stream>>>(xp_part, xdbl);

    // dt_proj + softplus: [8192,64] x [2048,64]^T -> delta bf16 [8192,2048]
    gemm_bt<1><<<dim3(64, 16), 256, 0, stream>>>(xdbl, XPN, w_dt, delta, nullptr, DI,
                                                 TOK, DI, DR, dt_proj_b, nullptr, nullptr, nullptr);

    // chunked selective scan
    scan_passA<<<dim3(8, 4, NCHUNK), 256, 0, stream>>>(delta, u, xdbl, A_log, qh, Sarr);
    scan_passB<<<512, 256, 0, stream>>>(qh, Sarr, A_log);
    scan_passC<<<dim3(8, 4, NCHUNK), 256, 0, stream>>>(delta, u, xdbl, xz, A_log, Dvec, qh, yg);

    // out_proj + gate + residual: [8192,2048] x [1024,2048]^T -> out f32 [8192,1024]
    gemm8<2><<<dim3(32, 8), 512, 0, stream>>>(yg, DI, w_out, nullptr, out, DM,
                                              TOK, DM, DI, x, th, sd);
}